// Round 15
// baseline (176.584 us; speedup 1.0000x reference)
//
#include <hip/hip_runtime.h>
#include <hip/hip_bf16.h>
#include <math.h>

typedef __bf16 bf16x8 __attribute__((ext_vector_type(8)));
typedef __bf16 bf16x4 __attribute__((ext_vector_type(4)));
typedef __bf16 bf16x2 __attribute__((ext_vector_type(2)));
typedef float f32x4 __attribute__((ext_vector_type(4)));
typedef float f32x16 __attribute__((ext_vector_type(16)));

static constexpr int DM = 1024;    // d_model
static constexpr int HD = 64;      // head dim
static constexpr size_t M1 = 1024 * 1024;

// pack two f32 -> u32 of two bf16 (compiler emits v_cvt_pk_bf16_f32)
__device__ __forceinline__ unsigned pk2(float a, float b) {
    union { __bf16 h[2]; unsigned u; } t;
    t.h[0] = (__bf16)a; t.h[1] = (__bf16)b;
    return t.u;
}

// async global->LDS, 16 B per lane; LDS dest = wave-uniform base + lane*16
typedef const __attribute__((address_space(1))) unsigned int* gp_t;
typedef __attribute__((address_space(3))) unsigned int* lp_t;
__device__ __forceinline__ void gload_lds16(const void* g, void* l) {
    __builtin_amdgcn_global_load_lds((gp_t)g, (lp_t)l, 16, 0, 0);
}

// ---------------------------------------------------------------------------
// Fused f32->bf16 convert of all 7 tensors, one launch.
// ---------------------------------------------------------------------------
__global__ void cvt_all(const float* __restrict__ x0, const float* __restrict__ x1,
                        const float* __restrict__ x2, const float* __restrict__ Wq,
                        const float* __restrict__ Wk, const float* __restrict__ Wv,
                        const float* __restrict__ Wo,
                        __bf16* __restrict__ xb0, __bf16* __restrict__ xb1,
                        __bf16* __restrict__ xb2, __bf16* __restrict__ Wqb,
                        __bf16* __restrict__ Wkb, __bf16* __restrict__ Wvb,
                        __bf16* __restrict__ Wob) {
    size_t i = (size_t)(blockIdx.x * blockDim.x + threadIdx.x) * 8;
    const float* in; __bf16* outp; size_t off;
    if      (i < 2 * M1)            { in = x0; outp = xb0; off = i; }
    else if (i < 3 * M1)            { in = x1; outp = xb1; off = i - 2 * M1; }
    else if (i < 3 * M1 + M1 / 2)   { in = x2; outp = xb2; off = i - 3 * M1; }
    else if (i < 6 * M1 + M1 / 2)   { in = Wq; outp = Wqb; off = i - (3 * M1 + M1 / 2); }
    else if (i < 9 * M1 + M1 / 2)   { in = Wk; outp = Wkb; off = i - (6 * M1 + M1 / 2); }
    else if (i < 10 * M1 + M1 / 2)  { in = Wv; outp = Wvb; off = i - (9 * M1 + M1 / 2); }
    else if (i < 11 * M1 + M1 / 2)  { in = Wo; outp = Wob; off = i - (10 * M1 + M1 / 2); }
    else return;
    const float4 a = *reinterpret_cast<const float4*>(in + off);
    const float4 b = *reinterpret_cast<const float4*>(in + off + 4);
    bf16x8 r;
    r[0] = (__bf16)a.x; r[1] = (__bf16)a.y; r[2] = (__bf16)a.z; r[3] = (__bf16)a.w;
    r[4] = (__bf16)b.x; r[5] = (__bf16)b.y; r[6] = (__bf16)b.z; r[7] = (__bf16)b.w;
    *reinterpret_cast<bf16x8*>(outp + off) = r;
}

// ---------------------------------------------------------------------------
// GEMM core v5: 128x256 block tile, 4 waves (2x2) of 64x128, BK=32, dbuf LDS.
// Per step/wave: 6 gload_lds (A 2, B 4) staged BEFORE compute; 12 ds_read_b128
// + 32 MFMA; one __syncthreads per step (drain overlapped by the 32 MFMAs).
// Coalesced staging + both-sides XOR swizzle (r13-verified pattern):
//   LDS rows of 32k (64 B); lane s: row=s>>2, chunk=(s&3)^((row^(row>>2))&3);
//   frag read at row*32 + (g^swz(row))*8.
// C/D layout: row=(lane>>4)*4+reg, col=lane&15 (m89-verified)
// ---------------------------------------------------------------------------
__device__ __forceinline__ void gemm_lds_core(const __bf16* __restrict__ A,
                                              const __bf16* __restrict__ W,
                                              int rb, int cb, int tix,
                                              __bf16* lA, __bf16* lB,
                                              f32x4 (&acc)[4][8]) {
    const int lane = tix & 63;
    const int w = tix >> 6;
    const int g = lane >> 4, t = lane & 15;
    // A staging: 2 insts, rows 0..127
    const int ar0 = tix >> 2;
    const int ar1 = ar0 + 64;
    const int ac0 = (tix & 3) ^ ((ar0 ^ (ar0 >> 2)) & 3);
    const int ac1 = (tix & 3) ^ ((ar1 ^ (ar1 >> 2)) & 3);
    const __bf16* aS0 = A + (size_t)(rb + ar0) * DM + ac0 * 8;
    const __bf16* aS1 = A + (size_t)(rb + ar1) * DM + ac1 * 8;
    const int dA0 = w * 512;             // elem offsets within A buffer (4096)
    const int dA1 = 2048 + w * 512;
    // B staging: 4 insts, rows 0..255
    const __bf16* bS[4];
    int dB[4];
#pragma unroll
    for (int j = 0; j < 4; ++j) {
        const int s = j * 256 + tix;
        const int row = s >> 2;
        const int c = (s & 3) ^ ((row ^ (row >> 2)) & 3);
        bS[j] = W + (size_t)(cb + row) * DM + c * 8;
        dB[j] = j * 2048 + w * 512;      // within B buffer (8192)
    }
    const int rw = (w >> 1) * 64, cw = (w & 1) * 128;
    int roA[4], roB[8];
#pragma unroll
    for (int i = 0; i < 4; ++i) {
        const int ra = rw + i * 16 + t;
        roA[i] = ra * 32 + ((g ^ ((ra ^ (ra >> 2)) & 3)) * 8);
    }
#pragma unroll
    for (int i = 0; i < 8; ++i) {
        const int rbr = cw + i * 16 + t;
        roB[i] = rbr * 32 + ((g ^ ((rbr ^ (rbr >> 2)) & 3)) * 8);
    }

#define STAGE_STEP(kk_, buf_)                                        \
    {                                                                \
        __bf16* nA = lA + (buf_) * 4096;                             \
        __bf16* nB = lB + (buf_) * 8192;                             \
        gload_lds16(aS0 + (kk_), nA + dA0);                          \
        gload_lds16(aS1 + (kk_), nA + dA1);                          \
        _Pragma("unroll")                                            \
        for (int j = 0; j < 4; ++j)                                  \
            gload_lds16(bS[j] + (kk_), nB + dB[j]);                  \
    }

    // prologue: stage step 0 into buffer 0
    STAGE_STEP(0, 0);
    __syncthreads();

    int cur = 0;
    for (int kk = 0; kk < DM; kk += 32) {
        if (kk + 32 < DM) STAGE_STEP(kk + 32, cur ^ 1);
        const __bf16* bA = lA + cur * 4096;
        const __bf16* bB = lB + cur * 8192;
        bf16x8 af[4], bfr[8];
#pragma unroll
        for (int i = 0; i < 4; ++i)
            af[i] = *reinterpret_cast<const bf16x8*>(bA + roA[i]);
#pragma unroll
        for (int i = 0; i < 8; ++i)
            bfr[i] = *reinterpret_cast<const bf16x8*>(bB + roB[i]);
#pragma unroll
        for (int mi = 0; mi < 4; ++mi)
#pragma unroll
            for (int ni = 0; ni < 8; ++ni)
                acc[mi][ni] = __builtin_amdgcn_mfma_f32_16x16x32_bf16(af[mi], bfr[ni], acc[mi][ni], 0, 0, 0);
        __syncthreads();     // drains next-step loads (issued before compute)
        cur ^= 1;
    }
#undef STAGE_STEP
}

// ---------------------------------------------------------------------------
// All pre-attention GEMMs, flat 1-D grid of 288 blocks (128x256 tiles):
//   z=0,2,4: Q proj + fused RoPE + 1/8 scale | z=1,3,5: K proj + RoPE
//   z=6: V proj -> transposed vt0 + fused avg-pool into vt1, vt2
// Chunked XCD swizzle: swz=(bid&7)*36+(bid>>3) (288=8*36, bijective);
// within-job column-major enumeration -> co-XCD blocks share W panels.
// ---------------------------------------------------------------------------
__global__ __launch_bounds__(256)
void gemm_pre(const __bf16* __restrict__ xb0, const __bf16* __restrict__ xb1,
              const __bf16* __restrict__ xb2, const __bf16* __restrict__ Wqb,
              const __bf16* __restrict__ Wkb, const __bf16* __restrict__ Wvb,
              const float* __restrict__ bq, const float* __restrict__ bk,
              const float* __restrict__ bv,
              __bf16* __restrict__ qb0, __bf16* __restrict__ kb0,
              __bf16* __restrict__ qb1, __bf16* __restrict__ kb1,
              __bf16* __restrict__ qb2, __bf16* __restrict__ kb2,
              __bf16* __restrict__ vt0, __bf16* __restrict__ vt1,
              __bf16* __restrict__ vt2) {
    __shared__ __align__(16) __bf16 lA[8192], lB[16384];   // 48 KB (2 buffers)
    const int bid = blockIdx.x;
    const int swz = (bid & 7) * 36 + (bid >> 3);
    int z, local, mblk;
    if      (swz < 64)  { z = 0; local = swz;       mblk = 16; }
    else if (swz < 128) { z = 1; local = swz - 64;  mblk = 16; }
    else if (swz < 160) { z = 2; local = swz - 128; mblk = 8;  }
    else if (swz < 192) { z = 3; local = swz - 160; mblk = 8;  }
    else if (swz < 208) { z = 4; local = swz - 192; mblk = 4;  }
    else if (swz < 224) { z = 5; local = swz - 208; mblk = 4;  }
    else                { z = 6; local = swz - 224; mblk = 16; }
    const __bf16* A; const __bf16* W; const float* bias; __bf16* out;
    switch (z) {
        case 0:  A = xb0; W = Wqb;          bias = bq;        out = qb0; break;
        case 1:  A = xb0; W = Wkb;          bias = bk;        out = kb0; break;
        case 2:  A = xb1; W = Wqb + M1;     bias = bq + 1024; out = qb1; break;
        case 3:  A = xb1; W = Wkb + M1;     bias = bk + 1024; out = kb1; break;
        case 4:  A = xb2; W = Wqb + 2 * M1; bias = bq + 2048; out = qb2; break;
        case 5:  A = xb2; W = Wkb + 2 * M1; bias = bk + 2048; out = kb2; break;
        default: A = xb0; W = Wvb;          bias = bv;        out = nullptr; break;
    }
    const int rb = (local % mblk) * 128;
    const int cb = (local / mblk) * 256;
    const int tix = threadIdx.x;
    f32x4 acc[4][8] = {};
    gemm_lds_core(A, W, rb, cb, tix, lA, lB, acc);

    const int lane = tix & 63;
    const int w = tix >> 6;
    const int g = lane >> 4, t = lane & 15;
    const int rbw = rb + (w >> 1) * 64;
    const int cbw = cb + (w & 1) * 128;    // 128-col span = 2 heads

    if (z == 6) {
        // V projection epilogue: transposed store + fused avg-pool
#pragma unroll
        for (int ni = 0; ni < 8; ++ni) {
            const int col = cbw + ni * 16 + t;          // d dim
            const float bb = bias[col];
#pragma unroll
            for (int mi = 0; mi < 4; ++mi) {
                const int row0 = rbw + mi * 16 + g * 4; // n dim
                const f32x4 a = acc[mi][ni];
                bf16x4 pk;
#pragma unroll
                for (int r = 0; r < 4; ++r) pk[r] = (__bf16)(a[r] + bb);
                *reinterpret_cast<bf16x4*>(vt0 + (size_t)col * 2048 + row0) = pk;
                bf16x2 p2;
                p2[0] = (__bf16)(0.5f * (a[0] + a[1]) + bb);
                p2[1] = (__bf16)(0.5f * (a[2] + a[3]) + bb);
                *reinterpret_cast<bf16x2*>(vt1 + (size_t)col * 1024 + row0 / 2) = p2;
                vt2[(size_t)col * 512 + row0 / 4] =
                    (__bf16)(0.25f * (a[0] + a[1] + a[2] + a[3]) + bb);
            }
        }
    } else {
        // Q/K epilogue with fused RoPE over the wave's 2 heads;
        // Q additionally scaled by 1/8. RoPE pair (j, j+32) = frags
        // (hh*4+ni, hh*4+ni+2) within head hh.
        const float qmul = (z & 1) ? 1.0f : 0.125f;
        const float ps = (float)(1 << (z >> 1));   // 1,2,4
#pragma unroll
        for (int hh = 0; hh < 2; ++hh) {
            const int cbh = cbw + hh * 64;
#pragma unroll
            for (int ni = 0; ni < 2; ++ni) {
                const int j = ni * 16 + t;         // [0,32) within head
                const float invf = __expf(-(float)j * 0.28782313662425576f);
                const float b1 = bias[cbh + j];
                const float b2 = bias[cbh + j + 32];
#pragma unroll
                for (int mi = 0; mi < 4; ++mi) {
#pragma unroll
                    for (int r = 0; r < 4; ++r) {
                        const int row = rbw + mi * 16 + g * 4 + r;
                        float c, s;
                        __sincosf((float)row * ps * invf, &s, &c);
                        const float x1 = acc[mi][hh * 4 + ni][r] + b1;
                        const float x2 = acc[mi][hh * 4 + ni + 2][r] + b2;
                        out[(size_t)row * DM + cbh + j]      = (__bf16)((x1 * c - x2 * s) * qmul);
                        out[(size_t)row * DM + cbh + j + 32] = (__bf16)((x1 * s + x2 * c) * qmul);
                    }
                }
            }
        }
    }
}

// ---------------------------------------------------------------------------
// MFMA flash attention v7 (unchanged from round 13, verified): 32-row waves,
// swapped QK^T, lane-local softmax, per-wave coalesced LDS staging of K/V,
// P-bounce in dead K region, split-K combine, XCD head affinity.
// ---------------------------------------------------------------------------
__global__ __launch_bounds__(256)
void attn_all(const __bf16* __restrict__ qb0, const __bf16* __restrict__ kb0,
              const __bf16* __restrict__ vt0, __bf16* __restrict__ ctx0,
              const __bf16* __restrict__ qb1, const __bf16* __restrict__ kb1,
              const __bf16* __restrict__ vt1, __bf16* __restrict__ ctx1,
              const __bf16* __restrict__ qb2, const __bf16* __restrict__ kb2,
              const __bf16* __restrict__ vt2, __bf16* __restrict__ ctx2) {
    __shared__ __align__(16) float shm[4 * 64 * 33];    // 33.8 KB
    const int bid = blockIdx.x;
    const int job = (bid & 7) * 224 + (bid >> 3);
    const int h = job / 112;
    int rem = job % 112;
    const __bf16 *qb, *kb, *vt; __bf16* ctx; int N, nq;
    if (rem < 64)      { qb = qb0; kb = kb0; vt = vt0; ctx = ctx0; N = 2048; nq = 64; }
    else if (rem < 96) { rem -= 64; qb = qb1; kb = kb1; vt = vt1; ctx = ctx1; N = 1024; nq = 32; }
    else               { rem -= 96; qb = qb2; kb = kb2; vt = vt2; ctx = ctx2; N = 512;  nq = 16; }
    const int qt = (rem & 1) ? (nq - 1 - (rem >> 1)) : (rem >> 1);
    const int lane = threadIdx.x & 63;
    const int w = threadIdx.x >> 6;
    const int q0 = qt * 32;
    const int lq = lane & 31;
    const int hi = lane >> 5;

    __bf16* Kl = (__bf16*)shm + (size_t)w * 4096;   // [32][64 elems] (4 KB)
    __bf16* Vl = Kl + 2048;                          // [64][32 elems] (4 KB)

    const __bf16* qp = qb + (size_t)(q0 + lq) * DM + h * HD + hi * 8;
    bf16x8 qf[4];
#pragma unroll
    for (int dc = 0; dc < 4; ++dc)
        qf[dc] = *reinterpret_cast<const bf16x8*>(qp + dc * 16);

    f32x16 o0 = {}, o1 = {};
    float lsum = 0.f;
    const int ktiles = qt + 1;

    const int krow = lane >> 3, kch = lane & 7;      // K: 8 lanes/row (128B)
    const int vrow = lane >> 2, vch = lane & 3;      // V: 4 lanes/row (64B)

    int koff[4];
#pragma unroll
    for (int dc = 0; dc < 4; ++dc)
        koff[dc] = lq * 64 + (((dc * 2 + hi) ^ (lq & 7)) * 8);
    const int v00o = lq * 32 + ((hi ^ (lq & 3)) * 8);
    const int v01o = lq * 32 + (((2 + hi) ^ (lq & 3)) * 8);
    const int v10o = (32 + lq) * 32 + ((hi ^ (lq & 3)) * 8);
    const int v11o = (32 + lq) * 32 + (((2 + hi) ^ (lq & 3)) * 8);

    unsigned* pw = (unsigned*)Kl + lq * 18;          // P-bounce inside K region
    const __bf16* prb = (const __bf16*)pw;

    for (int kt = w; kt < ktiles; kt += 4) {
        const int j0 = kt * 32;
#pragma unroll
        for (int j = 0; j < 4; ++j) {
            const int row = j * 8 + krow;
            gload_lds16(kb + (size_t)(j0 + row) * DM + h * HD + ((kch ^ (row & 7)) * 8),
                        Kl + j * 512);
        }
#pragma unroll
        for (int j = 0; j < 4; ++j) {
            const int row = j * 16 + vrow;
            gload_lds16(vt + (size_t)(h * HD + row) * N + j0 + ((vch ^ (row & 3)) * 8),
                        Vl + j * 512);
        }
        asm volatile("s_waitcnt vmcnt(0)" ::: "memory");

        bf16x8 kf[4];
#pragma unroll
        for (int dc = 0; dc < 4; ++dc)
            kf[dc] = *reinterpret_cast<const bf16x8*>(Kl + koff[dc]);
        const bf16x8 v00 = *reinterpret_cast<const bf16x8*>(Vl + v00o);
        const bf16x8 v01 = *reinterpret_cast<const bf16x8*>(Vl + v01o);
        const bf16x8 v10 = *reinterpret_cast<const bf16x8*>(Vl + v10o);
        const bf16x8 v11 = *reinterpret_cast<const bf16x8*>(Vl + v11o);

        f32x16 p = {};
        p = __builtin_amdgcn_mfma_f32_32x32x16_bf16(kf[0], qf[0], p, 0, 0, 0);
        p = __builtin_amdgcn_mfma_f32_32x32x16_bf16(kf[1], qf[1], p, 0, 0, 0);
        p = __builtin_amdgcn_mfma_f32_32x32x16_bf16(kf[2], qf[2], p, 0, 0, 0);
        p = __builtin_amdgcn_mfma_f32_32x32x16_bf16(kf[3], qf[3], p, 0, 0, 0);

#pragma unroll
        for (int r = 0; r < 16; ++r) {
            const int key = j0 + (r & 3) + 8 * (r >> 2) + 4 * hi;
            p[r] = (key <= q0 + lq) ? __expf(p[r]) : 0.f;
            lsum += p[r];
        }

        pw[2 * hi]      = pk2(p[0],  p[1]);
        pw[2 * hi + 1]  = pk2(p[2],  p[3]);
        pw[4 + 2 * hi]  = pk2(p[4],  p[5]);
        pw[5 + 2 * hi]  = pk2(p[6],  p[7]);
        pw[8 + 2 * hi]  = pk2(p[8],  p[9]);
        pw[9 + 2 * hi]  = pk2(p[10], p[11]);
        pw[12 + 2 * hi] = pk2(p[12], p[13]);
        pw[13 + 2 * hi] = pk2(p[14], p[15]);
        union U8 { bf16x4 half[2]; bf16x8 v; };
        U8 pf0, pf1;
        pf0.half[0] = *reinterpret_cast<const bf16x4*>(prb + hi * 8);
        pf0.half[1] = *reinterpret_cast<const bf16x4*>(prb + hi * 8 + 4);
        pf1.half[0] = *reinterpret_cast<const bf16x4*>(prb + 16 + hi * 8);
        pf1.half[1] = *reinterpret_cast<const bf16x4*>(prb + 16 + hi * 8 + 4);

        o0 = __builtin_amdgcn_mfma_f32_32x32x16_bf16(v00, pf0.v, o0, 0, 0, 0);
        o0 = __builtin_amdgcn_mfma_f32_32x32x16_bf16(v01, pf1.v, o0, 0, 0, 0);
        o1 = __builtin_amdgcn_mfma_f32_32x32x16_bf16(v10, pf0.v, o1, 0, 0, 0);
        o1 = __builtin_amdgcn_mfma_f32_32x32x16_bf16(v11, pf1.v, o1, 0, 0, 0);
    }

    __syncthreads();   // staging/P regions dead in all waves -> overlay combine
    float* cmb = shm;
    float* my = cmb + ((size_t)w * 64 + lane) * 33;
#pragma unroll
    for (int i = 0; i < 16; ++i) { my[i] = o0[i]; my[16 + i] = o1[i]; }
    my[32] = lsum;
    __syncthreads();
    float tot[8] = {};
    float lt = 0.f;
#pragma unroll
    for (int w2 = 0; w2 < 4; ++w2) {
        const float* src = cmb + ((size_t)w2 * 64 + lane) * 33;
#pragma unroll
        for (int j = 0; j < 8; ++j) tot[j] += src[8 * w + j];
        lt += src[32];
    }
    lt += __shfl_xor(lt, 32);
    const float inv = 1.0f / lt;
    const int dbase = 32 * (w >> 1) + 16 * (w & 1) + 4 * hi;
    __bf16* cp = ctx + (size_t)(q0 + lq) * DM + h * HD;
    bf16x4 s0, s1;
#pragma unroll
    for (int j = 0; j < 4; ++j) {
        s0[j] = (__bf16)(tot[j] * inv);
        s1[j] = (__bf16)(tot[4 + j] * inv);
    }
    *reinterpret_cast<bf16x4*>(cp + dbase) = s0;
    *reinterpret_cast<bf16x4*>(cp + dbase + 8) = s1;
}

// ---------------------------------------------------------------------------
// Output projections, flat grid of 112 blocks (8x14 chunked XCD swizzle),
// 128x256 tiles.
// ---------------------------------------------------------------------------
__global__ __launch_bounds__(256)
void gemm_out_all(const __bf16* __restrict__ c0, const __bf16* __restrict__ c1,
                  const __bf16* __restrict__ c2, const __bf16* __restrict__ Wob,
                  const float* __restrict__ bo, float* __restrict__ out) {
    __shared__ __align__(16) __bf16 lA[8192], lB[16384];
    const int bid = blockIdx.x;
    const int swz = (bid & 7) * 14 + (bid >> 3);     // 112 = 8*14
    int z, local, mblk;
    if      (swz < 64) { z = 0; local = swz;      mblk = 16; }
    else if (swz < 96) { z = 1; local = swz - 64; mblk = 8;  }
    else               { z = 2; local = swz - 96; mblk = 4;  }
    const __bf16* A; float* o;
    switch (z) {
        case 0:  A = c0; o = out;             break;
        case 1:  A = c1; o = out + 2048 * DM; break;
        default: A = c2; o = out + 3072 * DM; break;
    }
    const int rb = (local % mblk) * 128;
    const int cb = (local / mblk) * 256;
    const int tix = threadIdx.x;
    f32x4 acc[4][8] = {};
    gemm_lds_core(A, Wob, rb, cb, tix, lA, lB, acc);

    const int lane = tix & 63;
    const int w = tix >> 6;
    const int g = lane >> 4, t = lane & 15;
    const int rbw = rb + (w >> 1) * 64;
    const int cbw = cb + (w & 1) * 128;
#pragma unroll
    for (int ni = 0; ni < 8; ++ni) {
        const int col = cbw + ni * 16 + t;
        const float bb = bo[col];
#pragma unroll
        for (int mi = 0; mi < 4; ++mi) {
            const int row0 = rbw + mi * 16 + g * 4;
#pragma unroll
            for (int r = 0; r < 4; ++r)
                o[(size_t)(row0 + r) * DM + col] = acc[mi][ni][r] + bb;
        }
    }
}

// ---------------------------------------------------------------------------
extern "C" void kernel_launch(void* const* d_in, const int* in_sizes, int n_in,
                              void* d_out, int out_size, void* d_ws, size_t ws_size,
                              hipStream_t stream) {
    const float* x0 = (const float*)d_in[0];
    const float* x1 = (const float*)d_in[1];
    const float* x2 = (const float*)d_in[2];
    const float* Wq = (const float*)d_in[3];
    const float* bq = (const float*)d_in[4];
    const float* Wk = (const float*)d_in[5];
    const float* bk = (const float*)d_in[6];
    const float* Wv = (const float*)d_in[7];
    const float* bv = (const float*)d_in[8];
    const float* Wo = (const float*)d_in[9];
    const float* bo = (const float*)d_in[10];
    float* out = (float*)d_out;

    // bf16 workspace, ~39 MB
    __bf16* xb0 = (__bf16*)d_ws;        // 2M
    __bf16* xb1 = xb0 + 2 * M1;         // 1M
    __bf16* xb2 = xb1 + M1;             // 0.5M
    __bf16* Wqb = xb2 + M1 / 2;         // 3M
    __bf16* Wkb = Wqb + 3 * M1;         // 3M
    __bf16* Wvb = Wkb + 3 * M1;         // 1M
    __bf16* Wob = Wvb + M1;             // 1M
    __bf16* vt0 = Wob + M1;             // 2M
    __bf16* vt1 = vt0 + 2 * M1;         // 1M
    __bf16* vt2 = vt1 + M1;             // 0.5M
    __bf16* qb0 = vt2 + M1 / 2;         // 2M
    __bf16* kb0 = qb0 + 2 * M1;         // 2M
    __bf16* qb1 = kb0 + 2 * M1;         // 1M
    __bf16* kb1 = qb1 + M1;             // 1M
    __bf16* qb2 = kb1 + M1;             // 0.5M
    __bf16* kb2 = qb2 + M1 / 2;         // 0.5M

    // 1. convert everything to bf16
    cvt_all<<<5888, 256, 0, stream>>>(x0, x1, x2, Wq, Wk, Wv, Wo,
                                      xb0, xb1, xb2, Wqb, Wkb, Wvb, Wob);
    // 2. all pre-attention GEMMs (128x256 tiles, dbuf LDS, XCD chunked)
    gemm_pre<<<288, 256, 0, stream>>>(xb0, xb1, xb2, Wqb, Wkb, Wvb,
                                      bq, bk, bv,
                                      qb0, kb0, qb1, kb1, qb2, kb2,
                                      vt0, vt1, vt2);
    // 3. attention: per-wave coalesced K/V staging, split-K, XCD affinity
    attn_all<<<1792, 256, 0, stream>>>(qb0, kb0, vt0, qb0,
                                       qb1, kb1, vt1, qb1,
                                       qb2, kb2, vt2, qb2);
    // 4. output projections (128x256 tiles), f32 into d_out
    gemm_out_all<<<112, 256, 0, stream>>>(qb0, qb1, qb2, Wob, bo, out);
}

// Round 16
// 140.303 us; speedup vs baseline: 1.2586x; 1.2586x over previous
//
#include <hip/hip_runtime.h>
#include <hip/hip_bf16.h>
#include <math.h>

typedef __bf16 bf16x8 __attribute__((ext_vector_type(8)));
typedef __bf16 bf16x4 __attribute__((ext_vector_type(4)));
typedef __bf16 bf16x2 __attribute__((ext_vector_type(2)));
typedef float f32x4 __attribute__((ext_vector_type(4)));
typedef float f32x16 __attribute__((ext_vector_type(16)));

static constexpr int DM = 1024;    // d_model
static constexpr int HD = 64;      // head dim
static constexpr size_t M1 = 1024 * 1024;

// pack two f32 -> u32 of two bf16 (compiler emits v_cvt_pk_bf16_f32)
__device__ __forceinline__ unsigned pk2(float a, float b) {
    union { __bf16 h[2]; unsigned u; } t;
    t.h[0] = (__bf16)a; t.h[1] = (__bf16)b;
    return t.u;
}

// async global->LDS, 16 B per lane; LDS dest = wave-uniform base + lane*16
typedef const __attribute__((address_space(1))) unsigned int* gp_t;
typedef __attribute__((address_space(3))) unsigned int* lp_t;
__device__ __forceinline__ void gload_lds16(const void* g, void* l) {
    __builtin_amdgcn_global_load_lds((gp_t)g, (lp_t)l, 16, 0, 0);
}

// ---------------------------------------------------------------------------
// Fused f32->bf16 convert of all 7 tensors, one launch.
// ---------------------------------------------------------------------------
__global__ void cvt_all(const float* __restrict__ x0, const float* __restrict__ x1,
                        const float* __restrict__ x2, const float* __restrict__ Wq,
                        const float* __restrict__ Wk, const float* __restrict__ Wv,
                        const float* __restrict__ Wo,
                        __bf16* __restrict__ xb0, __bf16* __restrict__ xb1,
                        __bf16* __restrict__ xb2, __bf16* __restrict__ Wqb,
                        __bf16* __restrict__ Wkb, __bf16* __restrict__ Wvb,
                        __bf16* __restrict__ Wob) {
    size_t i = (size_t)(blockIdx.x * blockDim.x + threadIdx.x) * 8;
    const float* in; __bf16* outp; size_t off;
    if      (i < 2 * M1)            { in = x0; outp = xb0; off = i; }
    else if (i < 3 * M1)            { in = x1; outp = xb1; off = i - 2 * M1; }
    else if (i < 3 * M1 + M1 / 2)   { in = x2; outp = xb2; off = i - 3 * M1; }
    else if (i < 6 * M1 + M1 / 2)   { in = Wq; outp = Wqb; off = i - (3 * M1 + M1 / 2); }
    else if (i < 9 * M1 + M1 / 2)   { in = Wk; outp = Wkb; off = i - (6 * M1 + M1 / 2); }
    else if (i < 10 * M1 + M1 / 2)  { in = Wv; outp = Wvb; off = i - (9 * M1 + M1 / 2); }
    else if (i < 11 * M1 + M1 / 2)  { in = Wo; outp = Wob; off = i - (10 * M1 + M1 / 2); }
    else return;
    const float4 a = *reinterpret_cast<const float4*>(in + off);
    const float4 b = *reinterpret_cast<const float4*>(in + off + 4);
    bf16x8 r;
    r[0] = (__bf16)a.x; r[1] = (__bf16)a.y; r[2] = (__bf16)a.z; r[3] = (__bf16)a.w;
    r[4] = (__bf16)b.x; r[5] = (__bf16)b.y; r[6] = (__bf16)b.z; r[7] = (__bf16)b.w;
    *reinterpret_cast<bf16x8*>(outp + off) = r;
}

// ---------------------------------------------------------------------------
// GEMM core (EXACT r13 config — best measured): 128x128 block tile, 4 waves
// (2x2) of 64x64, BK=32, dbuf LDS, coalesced staging + both-sides XOR swizzle.
// LDS rows of 32k (64 B); lane s: row=s>>2, chunk=(s&3)^((row^(row>>2))&3);
// frag read at row*32 + (g^swz(row))*8.
// C/D layout: row=(lane>>4)*4+reg, col=lane&15 (m89-verified)
// ---------------------------------------------------------------------------
__device__ __forceinline__ void gemm_lds_core(const __bf16* __restrict__ A,
                                              const __bf16* __restrict__ W,
                                              int rb, int cb, int tix,
                                              __bf16* lA, __bf16* lB,
                                              f32x4 (&acc)[4][4]) {
    const int lane = tix & 63;
    const int w = tix >> 6;
    const int g = lane >> 4, t = lane & 15;
    const int r0 = tix >> 2;
    const int r1 = r0 + 64;
    const int c0 = (tix & 3) ^ ((r0 ^ (r0 >> 2)) & 3);
    const int c1 = (tix & 3) ^ ((r1 ^ (r1 >> 2)) & 3);
    const __bf16* a0 = A + (size_t)(rb + r0) * DM + c0 * 8;
    const __bf16* a1 = A + (size_t)(rb + r1) * DM + c1 * 8;
    const __bf16* b0 = W + (size_t)(cb + r0) * DM + c0 * 8;
    const __bf16* b1 = W + (size_t)(cb + r1) * DM + c1 * 8;
    const int d0 = w * 512;            // elem offset of wave's inst0 slot base
    const int d1 = 2048 + w * 512;     // inst1
    const int rw = (w >> 1) * 64, cw = (w & 1) * 64;
    int roA[4], roB[4];
#pragma unroll
    for (int i = 0; i < 4; ++i) {
        const int ra = rw + i * 16 + t;
        const int rbr = cw + i * 16 + t;
        roA[i] = ra * 32 + ((g ^ ((ra ^ (ra >> 2)) & 3)) * 8);
        roB[i] = rbr * 32 + ((g ^ ((rbr ^ (rbr >> 2)) & 3)) * 8);
    }

    // prologue: stage step 0 into buffer 0
    gload_lds16(a0, lA + d0);
    gload_lds16(a1, lA + d1);
    gload_lds16(b0, lB + d0);
    gload_lds16(b1, lB + d1);
    __syncthreads();

    int cur = 0;
    for (int kk = 0; kk < DM; kk += 32) {
        if (kk + 32 < DM) {
            __bf16* nA = lA + (cur ^ 1) * 4096;
            __bf16* nB = lB + (cur ^ 1) * 4096;
            gload_lds16(a0 + kk + 32, nA + d0);
            gload_lds16(a1 + kk + 32, nA + d1);
            gload_lds16(b0 + kk + 32, nB + d0);
            gload_lds16(b1 + kk + 32, nB + d1);
        }
        const __bf16* bA = lA + cur * 4096;
        const __bf16* bB = lB + cur * 4096;
        bf16x8 af[4], bfr[4];
#pragma unroll
        for (int i = 0; i < 4; ++i) {
            af[i]  = *reinterpret_cast<const bf16x8*>(bA + roA[i]);
            bfr[i] = *reinterpret_cast<const bf16x8*>(bB + roB[i]);
        }
#pragma unroll
        for (int mi = 0; mi < 4; ++mi)
#pragma unroll
            for (int ni = 0; ni < 4; ++ni)
                acc[mi][ni] = __builtin_amdgcn_mfma_f32_16x16x32_bf16(af[mi], bfr[ni], acc[mi][ni], 0, 0, 0);
        __syncthreads();    // drains next-step loads (issued before compute)
        cur ^= 1;
    }
}

// ---------------------------------------------------------------------------
// All pre-attention GEMMs, flat 1-D grid of 576 blocks (r13 config):
//   z=0,2,4: Q proj + fused RoPE + 1/8 scale | z=1,3,5: K proj + RoPE
//   z=6: V proj -> transposed vt0 + fused avg-pool into vt1, vt2
// Chunked XCD swizzle: swz=(bid&7)*72+(bid>>3) (576=8*72, bijective).
// ---------------------------------------------------------------------------
__global__ __launch_bounds__(256)
void gemm_pre(const __bf16* __restrict__ xb0, const __bf16* __restrict__ xb1,
              const __bf16* __restrict__ xb2, const __bf16* __restrict__ Wqb,
              const __bf16* __restrict__ Wkb, const __bf16* __restrict__ Wvb,
              const float* __restrict__ bq, const float* __restrict__ bk,
              const float* __restrict__ bv,
              __bf16* __restrict__ qb0, __bf16* __restrict__ kb0,
              __bf16* __restrict__ qb1, __bf16* __restrict__ kb1,
              __bf16* __restrict__ qb2, __bf16* __restrict__ kb2,
              __bf16* __restrict__ vt0, __bf16* __restrict__ vt1,
              __bf16* __restrict__ vt2) {
    __shared__ __align__(16) __bf16 lA[8192], lB[8192];   // 32 KB (2 buffers)
    const int bid = blockIdx.x;
    const int swz = (bid & 7) * 72 + (bid >> 3);
    int z, local, mblk;
    if      (swz < 128) { z = 0; local = swz;       mblk = 16; }
    else if (swz < 256) { z = 1; local = swz - 128; mblk = 16; }
    else if (swz < 320) { z = 2; local = swz - 256; mblk = 8;  }
    else if (swz < 384) { z = 3; local = swz - 320; mblk = 8;  }
    else if (swz < 416) { z = 4; local = swz - 384; mblk = 4;  }
    else if (swz < 448) { z = 5; local = swz - 416; mblk = 4;  }
    else                { z = 6; local = swz - 448; mblk = 16; }
    const __bf16* A; const __bf16* W; const float* bias; __bf16* out;
    switch (z) {
        case 0:  A = xb0; W = Wqb;          bias = bq;        out = qb0; break;
        case 1:  A = xb0; W = Wkb;          bias = bk;        out = kb0; break;
        case 2:  A = xb1; W = Wqb + M1;     bias = bq + 1024; out = qb1; break;
        case 3:  A = xb1; W = Wkb + M1;     bias = bk + 1024; out = kb1; break;
        case 4:  A = xb2; W = Wqb + 2 * M1; bias = bq + 2048; out = qb2; break;
        case 5:  A = xb2; W = Wkb + 2 * M1; bias = bk + 2048; out = kb2; break;
        default: A = xb0; W = Wvb;          bias = bv;        out = nullptr; break;
    }
    const int rb = (local % mblk) * 128;
    const int cb = (local / mblk) * 128;
    const int tix = threadIdx.x;
    f32x4 acc[4][4] = {};
    gemm_lds_core(A, W, rb, cb, tix, lA, lB, acc);

    const int lane = tix & 63;
    const int w = tix >> 6;
    const int g = lane >> 4, t = lane & 15;
    const int rbw = rb + (w >> 1) * 64;
    const int cbw = cb + (w & 1) * 64;     // head-aligned 64-col span

    if (z == 6) {
        // V projection epilogue: transposed store + fused avg-pool
#pragma unroll
        for (int ni = 0; ni < 4; ++ni) {
            const int col = cbw + ni * 16 + t;          // d dim
            const float bb = bias[col];
#pragma unroll
            for (int mi = 0; mi < 4; ++mi) {
                const int row0 = rbw + mi * 16 + g * 4; // n dim
                const f32x4 a = acc[mi][ni];
                bf16x4 pk;
#pragma unroll
                for (int r = 0; r < 4; ++r) pk[r] = (__bf16)(a[r] + bb);
                *reinterpret_cast<bf16x4*>(vt0 + (size_t)col * 2048 + row0) = pk;
                bf16x2 p2;
                p2[0] = (__bf16)(0.5f * (a[0] + a[1]) + bb);
                p2[1] = (__bf16)(0.5f * (a[2] + a[3]) + bb);
                *reinterpret_cast<bf16x2*>(vt1 + (size_t)col * 1024 + row0 / 2) = p2;
                vt2[(size_t)col * 512 + row0 / 4] =
                    (__bf16)(0.25f * (a[0] + a[1] + a[2] + a[3]) + bb);
            }
        }
    } else {
        // Q/K epilogue with fused RoPE; Q additionally scaled by 1/8
        const float qmul = (z & 1) ? 1.0f : 0.125f;
        const float ps = (float)(1 << (z >> 1));   // 1,2,4
#pragma unroll
        for (int ni = 0; ni < 2; ++ni) {
            const int j = ni * 16 + t;             // [0,32) within head
            const float invf = __expf(-(float)j * 0.28782313662425576f);
            const float b1 = bias[cbw + j];
            const float b2 = bias[cbw + j + 32];
#pragma unroll
            for (int mi = 0; mi < 4; ++mi) {
#pragma unroll
                for (int r = 0; r < 4; ++r) {
                    const int row = rbw + mi * 16 + g * 4 + r;
                    float c, s;
                    __sincosf((float)row * ps * invf, &s, &c);
                    const float x1 = acc[mi][ni][r] + b1;
                    const float x2 = acc[mi][ni + 2][r] + b2;
                    out[(size_t)row * DM + cbw + j]      = (__bf16)((x1 * c - x2 * s) * qmul);
                    out[(size_t)row * DM + cbw + j + 32] = (__bf16)((x1 * s + x2 * c) * qmul);
                }
            }
        }
    }
}

// ---------------------------------------------------------------------------
// MFMA flash attention v7.1: r13's proven v7 (32-row waves, swapped QK^T,
// lane-local softmax, per-wave coalesced LDS staging, P-bounce in dead K
// region, split-K combine, XCD head affinity) + two refinements:
//  - SPLIT COUNTED WAITS: issue K loads (4) then V loads (4); vmcnt(4) waits
//    only the K loads (oldest-4, m135 FIFO semantics) -> QK^T + softmax +
//    P-bounce run while V is still in flight; vmcnt(0) before V frag reads.
//  - T5 s_setprio(1) around both MFMA clusters (m191: +4-7% attn).
// ---------------------------------------------------------------------------
__global__ __launch_bounds__(256)
void attn_all(const __bf16* __restrict__ qb0, const __bf16* __restrict__ kb0,
              const __bf16* __restrict__ vt0, __bf16* __restrict__ ctx0,
              const __bf16* __restrict__ qb1, const __bf16* __restrict__ kb1,
              const __bf16* __restrict__ vt1, __bf16* __restrict__ ctx1,
              const __bf16* __restrict__ qb2, const __bf16* __restrict__ kb2,
              const __bf16* __restrict__ vt2, __bf16* __restrict__ ctx2) {
    __shared__ __align__(16) float shm[4 * 64 * 33];    // 33.8 KB
    const int bid = blockIdx.x;
    const int job = (bid & 7) * 224 + (bid >> 3);
    const int h = job / 112;
    int rem = job % 112;
    const __bf16 *qb, *kb, *vt; __bf16* ctx; int N, nq;
    if (rem < 64)      { qb = qb0; kb = kb0; vt = vt0; ctx = ctx0; N = 2048; nq = 64; }
    else if (rem < 96) { rem -= 64; qb = qb1; kb = kb1; vt = vt1; ctx = ctx1; N = 1024; nq = 32; }
    else               { rem -= 96; qb = qb2; kb = kb2; vt = vt2; ctx = ctx2; N = 512;  nq = 16; }
    const int qt = (rem & 1) ? (nq - 1 - (rem >> 1)) : (rem >> 1);
    const int lane = threadIdx.x & 63;
    const int w = threadIdx.x >> 6;
    const int q0 = qt * 32;
    const int lq = lane & 31;
    const int hi = lane >> 5;

    __bf16* Kl = (__bf16*)shm + (size_t)w * 4096;   // [32][64 elems] (4 KB)
    __bf16* Vl = Kl + 2048;                          // [64][32 elems] (4 KB)

    const __bf16* qp = qb + (size_t)(q0 + lq) * DM + h * HD + hi * 8;
    bf16x8 qf[4];
#pragma unroll
    for (int dc = 0; dc < 4; ++dc)
        qf[dc] = *reinterpret_cast<const bf16x8*>(qp + dc * 16);

    f32x16 o0 = {}, o1 = {};
    float lsum = 0.f;
    const int ktiles = qt + 1;

    const int krow = lane >> 3, kch = lane & 7;      // K: 8 lanes/row (128B)
    const int vrow = lane >> 2, vch = lane & 3;      // V: 4 lanes/row (64B)

    int koff[4];
#pragma unroll
    for (int dc = 0; dc < 4; ++dc)
        koff[dc] = lq * 64 + (((dc * 2 + hi) ^ (lq & 7)) * 8);
    const int v00o = lq * 32 + ((hi ^ (lq & 3)) * 8);
    const int v01o = lq * 32 + (((2 + hi) ^ (lq & 3)) * 8);
    const int v10o = (32 + lq) * 32 + ((hi ^ (lq & 3)) * 8);
    const int v11o = (32 + lq) * 32 + (((2 + hi) ^ (lq & 3)) * 8);

    unsigned* pw = (unsigned*)Kl + lq * 18;          // P-bounce inside K region
    const __bf16* prb = (const __bf16*)pw;

    for (int kt = w; kt < ktiles; kt += 4) {
        const int j0 = kt * 32;
        // issue K loads first (these are the oldest 4)
#pragma unroll
        for (int j = 0; j < 4; ++j) {
            const int row = j * 8 + krow;
            gload_lds16(kb + (size_t)(j0 + row) * DM + h * HD + ((kch ^ (row & 7)) * 8),
                        Kl + j * 512);
        }
        // then V loads (stay in flight across QK^T + softmax)
#pragma unroll
        for (int j = 0; j < 4; ++j) {
            const int row = j * 16 + vrow;
            gload_lds16(vt + (size_t)(h * HD + row) * N + j0 + ((vch ^ (row & 3)) * 8),
                        Vl + j * 512);
        }
        // wait only the 4 K loads (oldest); V continues in flight
        asm volatile("s_waitcnt vmcnt(4)" ::: "memory");

        bf16x8 kf[4];
#pragma unroll
        for (int dc = 0; dc < 4; ++dc)
            kf[dc] = *reinterpret_cast<const bf16x8*>(Kl + koff[dc]);

        f32x16 p = {};
        __builtin_amdgcn_s_setprio(1);
        p = __builtin_amdgcn_mfma_f32_32x32x16_bf16(kf[0], qf[0], p, 0, 0, 0);
        p = __builtin_amdgcn_mfma_f32_32x32x16_bf16(kf[1], qf[1], p, 0, 0, 0);
        p = __builtin_amdgcn_mfma_f32_32x32x16_bf16(kf[2], qf[2], p, 0, 0, 0);
        p = __builtin_amdgcn_mfma_f32_32x32x16_bf16(kf[3], qf[3], p, 0, 0, 0);
        __builtin_amdgcn_s_setprio(0);

#pragma unroll
        for (int r = 0; r < 16; ++r) {
            const int key = j0 + (r & 3) + 8 * (r >> 2) + 4 * hi;
            p[r] = (key <= q0 + lq) ? __expf(p[r]) : 0.f;
            lsum += p[r];
        }

        // P-bounce (K region dead: kf already in registers)
        pw[2 * hi]      = pk2(p[0],  p[1]);
        pw[2 * hi + 1]  = pk2(p[2],  p[3]);
        pw[4 + 2 * hi]  = pk2(p[4],  p[5]);
        pw[5 + 2 * hi]  = pk2(p[6],  p[7]);
        pw[8 + 2 * hi]  = pk2(p[8],  p[9]);
        pw[9 + 2 * hi]  = pk2(p[10], p[11]);
        pw[12 + 2 * hi] = pk2(p[12], p[13]);
        pw[13 + 2 * hi] = pk2(p[14], p[15]);
        union U8 { bf16x4 half[2]; bf16x8 v; };
        U8 pf0, pf1;
        pf0.half[0] = *reinterpret_cast<const bf16x4*>(prb + hi * 8);
        pf0.half[1] = *reinterpret_cast<const bf16x4*>(prb + hi * 8 + 4);
        pf1.half[0] = *reinterpret_cast<const bf16x4*>(prb + 16 + hi * 8);
        pf1.half[1] = *reinterpret_cast<const bf16x4*>(prb + 16 + hi * 8 + 4);

        // now require V
        asm volatile("s_waitcnt vmcnt(0)" ::: "memory");
        const bf16x8 v00 = *reinterpret_cast<const bf16x8*>(Vl + v00o);
        const bf16x8 v01 = *reinterpret_cast<const bf16x8*>(Vl + v01o);
        const bf16x8 v10 = *reinterpret_cast<const bf16x8*>(Vl + v10o);
        const bf16x8 v11 = *reinterpret_cast<const bf16x8*>(Vl + v11o);

        __builtin_amdgcn_s_setprio(1);
        o0 = __builtin_amdgcn_mfma_f32_32x32x16_bf16(v00, pf0.v, o0, 0, 0, 0);
        o0 = __builtin_amdgcn_mfma_f32_32x32x16_bf16(v01, pf1.v, o0, 0, 0, 0);
        o1 = __builtin_amdgcn_mfma_f32_32x32x16_bf16(v10, pf0.v, o1, 0, 0, 0);
        o1 = __builtin_amdgcn_mfma_f32_32x32x16_bf16(v11, pf1.v, o1, 0, 0, 0);
        __builtin_amdgcn_s_setprio(0);
    }

    __syncthreads();   // staging/P regions dead in all waves -> overlay combine
    float* cmb = shm;
    float* my = cmb + ((size_t)w * 64 + lane) * 33;
#pragma unroll
    for (int i = 0; i < 16; ++i) { my[i] = o0[i]; my[16 + i] = o1[i]; }
    my[32] = lsum;
    __syncthreads();
    float tot[8] = {};
    float lt = 0.f;
#pragma unroll
    for (int w2 = 0; w2 < 4; ++w2) {
        const float* src = cmb + ((size_t)w2 * 64 + lane) * 33;
#pragma unroll
        for (int j = 0; j < 8; ++j) tot[j] += src[8 * w + j];
        lt += src[32];
    }
    lt += __shfl_xor(lt, 32);
    const float inv = 1.0f / lt;
    const int dbase = 32 * (w >> 1) + 16 * (w & 1) + 4 * hi;
    __bf16* cp = ctx + (size_t)(q0 + lq) * DM + h * HD;
    bf16x4 s0, s1;
#pragma unroll
    for (int j = 0; j < 4; ++j) {
        s0[j] = (__bf16)(tot[j] * inv);
        s1[j] = (__bf16)(tot[4 + j] * inv);
    }
    *reinterpret_cast<bf16x4*>(cp + dbase) = s0;
    *reinterpret_cast<bf16x4*>(cp + dbase + 8) = s1;
}

// ---------------------------------------------------------------------------
// Output projections, flat grid of 224 blocks (8x28 chunked XCD swizzle),
// exact r13 config.
// ---------------------------------------------------------------------------
__global__ __launch_bounds__(256)
void gemm_out_all(const __bf16* __restrict__ c0, const __bf16* __restrict__ c1,
                  const __bf16* __restrict__ c2, const __bf16* __restrict__ Wob,
                  const float* __restrict__ bo, float* __restrict__ out) {
    __shared__ __align__(16) __bf16 lA[8192], lB[8192];
    const int bid = blockIdx.x;
    const int swz = (bid & 7) * 28 + (bid >> 3);     // 224 = 8*28
    int z, local, mblk;
    if      (swz < 128) { z = 0; local = swz;       mblk = 16; }
    else if (swz < 192) { z = 1; local = swz - 128; mblk = 8;  }
    else                { z = 2; local = swz - 192; mblk = 4;  }
    const __bf16* A; float* o;
    switch (z) {
        case 0:  A = c0; o = out;             break;
        case 1:  A = c1; o = out + 2048 * DM; break;
        default: A = c2; o = out + 3072 * DM; break;
    }
    const int rb = (local % mblk) * 128;
    const int cb = (local / mblk) * 128;
    const int tix = threadIdx.x;
    f32x4 acc[4][4] = {};
    gemm_lds_core(A, Wob, rb, cb, tix, lA, lB, acc);

    const int lane = tix & 63;
    const int w = tix >> 6;
    const int g = lane >> 4, t = lane & 15;
    const int rbw = rb + (w >> 1) * 64;
    const int cbw = cb + (w & 1) * 64;
#pragma unroll
    for (int ni = 0; ni < 4; ++ni) {
        const int col = cbw + ni * 16 + t;
        const float bb = bo[col];
#pragma unroll
        for (int mi = 0; mi < 4; ++mi) {
            const int row0 = rbw + mi * 16 + g * 4;
#pragma unroll
            for (int r = 0; r < 4; ++r)
                o[(size_t)(row0 + r) * DM + col] = acc[mi][ni][r] + bb;
        }
    }
}

// ---------------------------------------------------------------------------
extern "C" void kernel_launch(void* const* d_in, const int* in_sizes, int n_in,
                              void* d_out, int out_size, void* d_ws, size_t ws_size,
                              hipStream_t stream) {
    const float* x0 = (const float*)d_in[0];
    const float* x1 = (const float*)d_in[1];
    const float* x2 = (const float*)d_in[2];
    const float* Wq = (const float*)d_in[3];
    const float* bq = (const float*)d_in[4];
    const float* Wk = (const float*)d_in[5];
    const float* bk = (const float*)d_in[6];
    const float* Wv = (const float*)d_in[7];
    const float* bv = (const float*)d_in[8];
    const float* Wo = (const float*)d_in[9];
    const float* bo = (const float*)d_in[10];
    float* out = (float*)d_out;

    // bf16 workspace, ~39 MB
    __bf16* xb0 = (__bf16*)d_ws;        // 2M
    __bf16* xb1 = xb0 + 2 * M1;         // 1M
    __bf16* xb2 = xb1 + M1;             // 0.5M
    __bf16* Wqb = xb2 + M1 / 2;         // 3M
    __bf16* Wkb = Wqb + 3 * M1;         // 3M
    __bf16* Wvb = Wkb + 3 * M1;         // 1M
    __bf16* Wob = Wvb + M1;             // 1M
    __bf16* vt0 = Wob + M1;             // 2M
    __bf16* vt1 = vt0 + 2 * M1;         // 1M
    __bf16* vt2 = vt1 + M1;             // 0.5M
    __bf16* qb0 = vt2 + M1 / 2;         // 2M
    __bf16* kb0 = qb0 + 2 * M1;         // 2M
    __bf16* qb1 = kb0 + 2 * M1;         // 1M
    __bf16* kb1 = qb1 + M1;             // 1M
    __bf16* qb2 = kb1 + M1;             // 0.5M
    __bf16* kb2 = qb2 + M1 / 2;         // 0.5M

    // 1. convert everything to bf16
    cvt_all<<<5888, 256, 0, stream>>>(x0, x1, x2, Wq, Wk, Wv, Wo,
                                      xb0, xb1, xb2, Wqb, Wkb, Wvb, Wob);
    // 2. all pre-attention GEMMs (r13 config: coalesced dbuf LDS core)
    gemm_pre<<<576, 256, 0, stream>>>(xb0, xb1, xb2, Wqb, Wkb, Wvb,
                                      bq, bk, bv,
                                      qb0, kb0, qb1, kb1, qb2, kb2,
                                      vt0, vt1, vt2);
    // 3. attention: split-wait K/V staging + setprio, split-K, XCD affinity
    attn_all<<<1792, 256, 0, stream>>>(qb0, kb0, vt0, qb0,
                                       qb1, kb1, vt1, qb1,
                                       qb2, kb2, vt2, qb2);
    // 4. output projections, f32 into d_out
    gemm_out_all<<<224, 256, 0, stream>>>(qb0, qb1, qb2, Wob, bo, out);
}

// Round 17
// 124.653 us; speedup vs baseline: 1.4166x; 1.1255x over previous
//
#include <hip/hip_runtime.h>
#include <hip/hip_bf16.h>
#include <math.h>

typedef __bf16 bf16x8 __attribute__((ext_vector_type(8)));
typedef __bf16 bf16x4 __attribute__((ext_vector_type(4)));
typedef __bf16 bf16x2 __attribute__((ext_vector_type(2)));
typedef float f32x4 __attribute__((ext_vector_type(4)));
typedef float f32x16 __attribute__((ext_vector_type(16)));

static constexpr int DM = 1024;    // d_model
static constexpr int HD = 64;      // head dim
static constexpr size_t M1 = 1024 * 1024;

// pack two f32 -> u32 of two bf16 (compiler emits v_cvt_pk_bf16_f32)
__device__ __forceinline__ unsigned pk2(float a, float b) {
    union { __bf16 h[2]; unsigned u; } t;
    t.h[0] = (__bf16)a; t.h[1] = (__bf16)b;
    return t.u;
}

// async global->LDS, 16 B per lane; LDS dest = wave-uniform base + lane*16
typedef const __attribute__((address_space(1))) unsigned int* gp_t;
typedef __attribute__((address_space(3))) unsigned int* lp_t;
__device__ __forceinline__ void gload_lds16(const void* g, void* l) {
    __builtin_amdgcn_global_load_lds((gp_t)g, (lp_t)l, 16, 0, 0);
}

// ---------------------------------------------------------------------------
// Fused f32->bf16 convert of all 7 tensors, one launch.
// ---------------------------------------------------------------------------
__global__ void cvt_all(const float* __restrict__ x0, const float* __restrict__ x1,
                        const float* __restrict__ x2, const float* __restrict__ Wq,
                        const float* __restrict__ Wk, const float* __restrict__ Wv,
                        const float* __restrict__ Wo,
                        __bf16* __restrict__ xb0, __bf16* __restrict__ xb1,
                        __bf16* __restrict__ xb2, __bf16* __restrict__ Wqb,
                        __bf16* __restrict__ Wkb, __bf16* __restrict__ Wvb,
                        __bf16* __restrict__ Wob) {
    size_t i = (size_t)(blockIdx.x * blockDim.x + threadIdx.x) * 8;
    const float* in; __bf16* outp; size_t off;
    if      (i < 2 * M1)            { in = x0; outp = xb0; off = i; }
    else if (i < 3 * M1)            { in = x1; outp = xb1; off = i - 2 * M1; }
    else if (i < 3 * M1 + M1 / 2)   { in = x2; outp = xb2; off = i - 3 * M1; }
    else if (i < 6 * M1 + M1 / 2)   { in = Wq; outp = Wqb; off = i - (3 * M1 + M1 / 2); }
    else if (i < 9 * M1 + M1 / 2)   { in = Wk; outp = Wkb; off = i - (6 * M1 + M1 / 2); }
    else if (i < 10 * M1 + M1 / 2)  { in = Wv; outp = Wvb; off = i - (9 * M1 + M1 / 2); }
    else if (i < 11 * M1 + M1 / 2)  { in = Wo; outp = Wob; off = i - (10 * M1 + M1 / 2); }
    else return;
    const float4 a = *reinterpret_cast<const float4*>(in + off);
    const float4 b = *reinterpret_cast<const float4*>(in + off + 4);
    bf16x8 r;
    r[0] = (__bf16)a.x; r[1] = (__bf16)a.y; r[2] = (__bf16)a.z; r[3] = (__bf16)a.w;
    r[4] = (__bf16)b.x; r[5] = (__bf16)b.y; r[6] = (__bf16)b.z; r[7] = (__bf16)b.w;
    *reinterpret_cast<bf16x8*>(outp + off) = r;
}

// ---------------------------------------------------------------------------
// GEMM half-K core (r13-proven layout, K-range 512): 128x128 tile, one
// 4-wave GROUP (ltix 0..255) of 64x64 waves, BK=32, dbuf LDS (2x4096 elems
// per operand), coalesced staging + both-sides XOR swizzle.
// Both groups of a 512-thread block call this in lockstep (same barrier
// count: 1 prologue + 16 steps).
// C/D layout: row=(lane>>4)*4+reg, col=lane&15 (m89-verified)
// ---------------------------------------------------------------------------
__device__ __forceinline__ void gemm_lds_core_g(const __bf16* __restrict__ A,
                                                const __bf16* __restrict__ W,
                                                int rb, int cb, int ltix,
                                                __bf16* lA, __bf16* lB,
                                                f32x4 (&acc)[4][4]) {
    const int lane = ltix & 63;
    const int w = ltix >> 6;
    const int g = lane >> 4, t = lane & 15;
    const int r0 = ltix >> 2;
    const int r1 = r0 + 64;
    const int c0 = (ltix & 3) ^ ((r0 ^ (r0 >> 2)) & 3);
    const int c1 = (ltix & 3) ^ ((r1 ^ (r1 >> 2)) & 3);
    const __bf16* a0 = A + (size_t)(rb + r0) * DM + c0 * 8;
    const __bf16* a1 = A + (size_t)(rb + r1) * DM + c1 * 8;
    const __bf16* b0 = W + (size_t)(cb + r0) * DM + c0 * 8;
    const __bf16* b1 = W + (size_t)(cb + r1) * DM + c1 * 8;
    const int d0 = w * 512;            // elem offset of wave's inst0 slot base
    const int d1 = 2048 + w * 512;     // inst1
    const int rw = (w >> 1) * 64, cw = (w & 1) * 64;
    int roA[4], roB[4];
#pragma unroll
    for (int i = 0; i < 4; ++i) {
        const int ra = rw + i * 16 + t;
        const int rbr = cw + i * 16 + t;
        roA[i] = ra * 32 + ((g ^ ((ra ^ (ra >> 2)) & 3)) * 8);
        roB[i] = rbr * 32 + ((g ^ ((rbr ^ (rbr >> 2)) & 3)) * 8);
    }

    // prologue: stage step 0 into buffer 0
    gload_lds16(a0, lA + d0);
    gload_lds16(a1, lA + d1);
    gload_lds16(b0, lB + d0);
    gload_lds16(b1, lB + d1);
    __syncthreads();

    int cur = 0;
    for (int kk = 0; kk < 512; kk += 32) {
        if (kk + 32 < 512) {
            __bf16* nA = lA + (cur ^ 1) * 4096;
            __bf16* nB = lB + (cur ^ 1) * 4096;
            gload_lds16(a0 + kk + 32, nA + d0);
            gload_lds16(a1 + kk + 32, nA + d1);
            gload_lds16(b0 + kk + 32, nB + d0);
            gload_lds16(b1 + kk + 32, nB + d1);
        }
        const __bf16* bA = lA + cur * 4096;
        const __bf16* bB = lB + cur * 4096;
        bf16x8 af[4], bfr[4];
#pragma unroll
        for (int i = 0; i < 4; ++i) {
            af[i]  = *reinterpret_cast<const bf16x8*>(bA + roA[i]);
            bfr[i] = *reinterpret_cast<const bf16x8*>(bB + roB[i]);
        }
#pragma unroll
        for (int mi = 0; mi < 4; ++mi)
#pragma unroll
            for (int ni = 0; ni < 4; ++ni)
                acc[mi][ni] = __builtin_amdgcn_mfma_f32_16x16x32_bf16(af[mi], bfr[ni], acc[mi][ni], 0, 0, 0);
        __syncthreads();    // drains next-step loads (issued before compute)
        cur ^= 1;
    }
}

// split-K combine helpers: layout cmbF[i][wq*64+lane], i in 0..63 — each i is
// a 256-float row, consecutive lanes -> consecutive banks (conflict-free).
__device__ __forceinline__ void spillAcc(float* cmbF, int wq, int lane,
                                         const f32x4 (&acc)[4][4]) {
#pragma unroll
    for (int i = 0; i < 16; ++i) {
        const f32x4 v = acc[i >> 2][i & 3];
#pragma unroll
        for (int r = 0; r < 4; ++r)
            cmbF[(size_t)(i * 4 + r) * 256 + wq * 64 + lane] = v[r];
    }
}
__device__ __forceinline__ void addAcc(const float* cmbF, int wq, int lane,
                                       f32x4 (&acc)[4][4]) {
#pragma unroll
    for (int i = 0; i < 16; ++i) {
#pragma unroll
        for (int r = 0; r < 4; ++r)
            acc[i >> 2][i & 3][r] += cmbF[(size_t)(i * 4 + r) * 256 + wq * 64 + lane];
    }
}

// ---------------------------------------------------------------------------
// All pre-attention GEMMs, flat 1-D grid of 576 blocks x 512 threads.
// SPLIT-K WITHIN BLOCK: group 0 (tix<256) computes K 0..511, group 1
// computes K 512..1023 on the same 128x128 tile; LDS combine (overlaid on
// dead staging) then group 0 runs the epilogue.
//   z=0,2,4: Q proj + fused RoPE + 1/8 scale | z=1,3,5: K proj + RoPE
//   z=6: V proj -> transposed vt0 + fused avg-pool into vt1, vt2
// Chunked XCD swizzle: swz=(bid&7)*72+(bid>>3) (576=8*72, bijective).
// ---------------------------------------------------------------------------
__global__ __launch_bounds__(512)
void gemm_pre(const __bf16* __restrict__ xb0, const __bf16* __restrict__ xb1,
              const __bf16* __restrict__ xb2, const __bf16* __restrict__ Wqb,
              const __bf16* __restrict__ Wkb, const __bf16* __restrict__ Wvb,
              const float* __restrict__ bq, const float* __restrict__ bk,
              const float* __restrict__ bv,
              __bf16* __restrict__ qb0, __bf16* __restrict__ kb0,
              __bf16* __restrict__ qb1, __bf16* __restrict__ kb1,
              __bf16* __restrict__ qb2, __bf16* __restrict__ kb2,
              __bf16* __restrict__ vt0, __bf16* __restrict__ vt1,
              __bf16* __restrict__ vt2) {
    __shared__ __align__(16) __bf16 lsh[32768];   // 64 KB
    const int bid = blockIdx.x;
    const int swz = (bid & 7) * 72 + (bid >> 3);
    int z, local, mblk;
    if      (swz < 128) { z = 0; local = swz;       mblk = 16; }
    else if (swz < 256) { z = 1; local = swz - 128; mblk = 16; }
    else if (swz < 320) { z = 2; local = swz - 256; mblk = 8;  }
    else if (swz < 384) { z = 3; local = swz - 320; mblk = 8;  }
    else if (swz < 416) { z = 4; local = swz - 384; mblk = 4;  }
    else if (swz < 448) { z = 5; local = swz - 416; mblk = 4;  }
    else                { z = 6; local = swz - 448; mblk = 16; }
    const __bf16* A; const __bf16* W; const float* bias; __bf16* out;
    switch (z) {
        case 0:  A = xb0; W = Wqb;          bias = bq;        out = qb0; break;
        case 1:  A = xb0; W = Wkb;          bias = bk;        out = kb0; break;
        case 2:  A = xb1; W = Wqb + M1;     bias = bq + 1024; out = qb1; break;
        case 3:  A = xb1; W = Wkb + M1;     bias = bk + 1024; out = kb1; break;
        case 4:  A = xb2; W = Wqb + 2 * M1; bias = bq + 2048; out = qb2; break;
        case 5:  A = xb2; W = Wkb + 2 * M1; bias = bk + 2048; out = kb2; break;
        default: A = xb0; W = Wvb;          bias = bv;        out = nullptr; break;
    }
    const int rb = (local % mblk) * 128;
    const int cb = (local / mblk) * 128;
    const int tix = threadIdx.x;
    const int grp = tix >> 8;          // K-half
    const int ltix = tix & 255;
    __bf16* lA = lsh + grp * 8192;             // 16 KB per group (2 buffers)
    __bf16* lB = lsh + 16384 + grp * 8192;
    f32x4 acc[4][4] = {};
    gemm_lds_core_g(A + grp * 512, W + grp * 512, rb, cb, ltix, lA, lB, acc);

    // split-K combine (staging dead after the loop's final barrier)
    float* cmbF = (float*)lsh;                 // 16384 floats = 64 KB
    const int lane = ltix & 63;
    const int wq = ltix >> 6;
    if (grp == 1) spillAcc(cmbF, wq, lane, acc);
    __syncthreads();
    if (grp == 1) return;                      // no barriers below
    addAcc(cmbF, wq, lane, acc);

    const int g = lane >> 4, t = lane & 15;
    const int rbw = rb + (wq >> 1) * 64;
    const int cbw = cb + (wq & 1) * 64;        // head-aligned 64-col span

    if (z == 6) {
        // V projection epilogue: transposed store + fused avg-pool
#pragma unroll
        for (int ni = 0; ni < 4; ++ni) {
            const int col = cbw + ni * 16 + t;          // d dim
            const float bb = bias[col];
#pragma unroll
            for (int mi = 0; mi < 4; ++mi) {
                const int row0 = rbw + mi * 16 + g * 4; // n dim
                const f32x4 a = acc[mi][ni];
                bf16x4 pk;
#pragma unroll
                for (int r = 0; r < 4; ++r) pk[r] = (__bf16)(a[r] + bb);
                *reinterpret_cast<bf16x4*>(vt0 + (size_t)col * 2048 + row0) = pk;
                bf16x2 p2;
                p2[0] = (__bf16)(0.5f * (a[0] + a[1]) + bb);
                p2[1] = (__bf16)(0.5f * (a[2] + a[3]) + bb);
                *reinterpret_cast<bf16x2*>(vt1 + (size_t)col * 1024 + row0 / 2) = p2;
                vt2[(size_t)col * 512 + row0 / 4] =
                    (__bf16)(0.25f * (a[0] + a[1] + a[2] + a[3]) + bb);
            }
        }
    } else {
        // Q/K epilogue with fused RoPE; Q additionally scaled by 1/8
        const float qmul = (z & 1) ? 1.0f : 0.125f;
        const float ps = (float)(1 << (z >> 1));   // 1,2,4
#pragma unroll
        for (int ni = 0; ni < 2; ++ni) {
            const int j = ni * 16 + t;             // [0,32) within head
            const float invf = __expf(-(float)j * 0.28782313662425576f);
            const float b1 = bias[cbw + j];
            const float b2 = bias[cbw + j + 32];
#pragma unroll
            for (int mi = 0; mi < 4; ++mi) {
#pragma unroll
                for (int r = 0; r < 4; ++r) {
                    const int row = rbw + mi * 16 + g * 4 + r;
                    float c, s;
                    __sincosf((float)row * ps * invf, &s, &c);
                    const float x1 = acc[mi][ni][r] + b1;
                    const float x2 = acc[mi][ni + 2][r] + b2;
                    out[(size_t)row * DM + cbw + j]      = (__bf16)((x1 * c - x2 * s) * qmul);
                    out[(size_t)row * DM + cbw + j + 32] = (__bf16)((x1 * s + x2 * c) * qmul);
                }
            }
        }
    }
}

// ---------------------------------------------------------------------------
// MFMA flash attention v7.1 (unchanged from r16, verified): 32-row waves,
// swapped QK^T, lane-local softmax, per-wave coalesced LDS staging with
// split counted waits (vmcnt(4) K / vmcnt(0) V), P-bounce in dead K region,
// T5 setprio around MFMA clusters, split-K combine, XCD head affinity.
// ---------------------------------------------------------------------------
__global__ __launch_bounds__(256)
void attn_all(const __bf16* __restrict__ qb0, const __bf16* __restrict__ kb0,
              const __bf16* __restrict__ vt0, __bf16* __restrict__ ctx0,
              const __bf16* __restrict__ qb1, const __bf16* __restrict__ kb1,
              const __bf16* __restrict__ vt1, __bf16* __restrict__ ctx1,
              const __bf16* __restrict__ qb2, const __bf16* __restrict__ kb2,
              const __bf16* __restrict__ vt2, __bf16* __restrict__ ctx2) {
    __shared__ __align__(16) float shm[4 * 64 * 33];    // 33.8 KB
    const int bid = blockIdx.x;
    const int job = (bid & 7) * 224 + (bid >> 3);
    const int h = job / 112;
    int rem = job % 112;
    const __bf16 *qb, *kb, *vt; __bf16* ctx; int N, nq;
    if (rem < 64)      { qb = qb0; kb = kb0; vt = vt0; ctx = ctx0; N = 2048; nq = 64; }
    else if (rem < 96) { rem -= 64; qb = qb1; kb = kb1; vt = vt1; ctx = ctx1; N = 1024; nq = 32; }
    else               { rem -= 96; qb = qb2; kb = kb2; vt = vt2; ctx = ctx2; N = 512;  nq = 16; }
    const int qt = (rem & 1) ? (nq - 1 - (rem >> 1)) : (rem >> 1);
    const int lane = threadIdx.x & 63;
    const int w = threadIdx.x >> 6;
    const int q0 = qt * 32;
    const int lq = lane & 31;
    const int hi = lane >> 5;

    __bf16* Kl = (__bf16*)shm + (size_t)w * 4096;   // [32][64 elems] (4 KB)
    __bf16* Vl = Kl + 2048;                          // [64][32 elems] (4 KB)

    const __bf16* qp = qb + (size_t)(q0 + lq) * DM + h * HD + hi * 8;
    bf16x8 qf[4];
#pragma unroll
    for (int dc = 0; dc < 4; ++dc)
        qf[dc] = *reinterpret_cast<const bf16x8*>(qp + dc * 16);

    f32x16 o0 = {}, o1 = {};
    float lsum = 0.f;
    const int ktiles = qt + 1;

    const int krow = lane >> 3, kch = lane & 7;      // K: 8 lanes/row (128B)
    const int vrow = lane >> 2, vch = lane & 3;      // V: 4 lanes/row (64B)

    int koff[4];
#pragma unroll
    for (int dc = 0; dc < 4; ++dc)
        koff[dc] = lq * 64 + (((dc * 2 + hi) ^ (lq & 7)) * 8);
    const int v00o = lq * 32 + ((hi ^ (lq & 3)) * 8);
    const int v01o = lq * 32 + (((2 + hi) ^ (lq & 3)) * 8);
    const int v10o = (32 + lq) * 32 + ((hi ^ (lq & 3)) * 8);
    const int v11o = (32 + lq) * 32 + (((2 + hi) ^ (lq & 3)) * 8);

    unsigned* pw = (unsigned*)Kl + lq * 18;          // P-bounce inside K region
    const __bf16* prb = (const __bf16*)pw;

    for (int kt = w; kt < ktiles; kt += 4) {
        const int j0 = kt * 32;
        // issue K loads first (these are the oldest 4)
#pragma unroll
        for (int j = 0; j < 4; ++j) {
            const int row = j * 8 + krow;
            gload_lds16(kb + (size_t)(j0 + row) * DM + h * HD + ((kch ^ (row & 7)) * 8),
                        Kl + j * 512);
        }
        // then V loads (stay in flight across QK^T + softmax)
#pragma unroll
        for (int j = 0; j < 4; ++j) {
            const int row = j * 16 + vrow;
            gload_lds16(vt + (size_t)(h * HD + row) * N + j0 + ((vch ^ (row & 3)) * 8),
                        Vl + j * 512);
        }
        // wait only the 4 K loads (oldest); V continues in flight
        asm volatile("s_waitcnt vmcnt(4)" ::: "memory");

        bf16x8 kf[4];
#pragma unroll
        for (int dc = 0; dc < 4; ++dc)
            kf[dc] = *reinterpret_cast<const bf16x8*>(Kl + koff[dc]);

        f32x16 p = {};
        __builtin_amdgcn_s_setprio(1);
        p = __builtin_amdgcn_mfma_f32_32x32x16_bf16(kf[0], qf[0], p, 0, 0, 0);
        p = __builtin_amdgcn_mfma_f32_32x32x16_bf16(kf[1], qf[1], p, 0, 0, 0);
        p = __builtin_amdgcn_mfma_f32_32x32x16_bf16(kf[2], qf[2], p, 0, 0, 0);
        p = __builtin_amdgcn_mfma_f32_32x32x16_bf16(kf[3], qf[3], p, 0, 0, 0);
        __builtin_amdgcn_s_setprio(0);

#pragma unroll
        for (int r = 0; r < 16; ++r) {
            const int key = j0 + (r & 3) + 8 * (r >> 2) + 4 * hi;
            p[r] = (key <= q0 + lq) ? __expf(p[r]) : 0.f;
            lsum += p[r];
        }

        // P-bounce (K region dead: kf already in registers)
        pw[2 * hi]      = pk2(p[0],  p[1]);
        pw[2 * hi + 1]  = pk2(p[2],  p[3]);
        pw[4 + 2 * hi]  = pk2(p[4],  p[5]);
        pw[5 + 2 * hi]  = pk2(p[6],  p[7]);
        pw[8 + 2 * hi]  = pk2(p[8],  p[9]);
        pw[9 + 2 * hi]  = pk2(p[10], p[11]);
        pw[12 + 2 * hi] = pk2(p[12], p[13]);
        pw[13 + 2 * hi] = pk2(p[14], p[15]);
        union U8 { bf16x4 half[2]; bf16x8 v; };
        U8 pf0, pf1;
        pf0.half[0] = *reinterpret_cast<const bf16x4*>(prb + hi * 8);
        pf0.half[1] = *reinterpret_cast<const bf16x4*>(prb + hi * 8 + 4);
        pf1.half[0] = *reinterpret_cast<const bf16x4*>(prb + 16 + hi * 8);
        pf1.half[1] = *reinterpret_cast<const bf16x4*>(prb + 16 + hi * 8 + 4);

        // now require V
        asm volatile("s_waitcnt vmcnt(0)" ::: "memory");
        const bf16x8 v00 = *reinterpret_cast<const bf16x8*>(Vl + v00o);
        const bf16x8 v01 = *reinterpret_cast<const bf16x8*>(Vl + v01o);
        const bf16x8 v10 = *reinterpret_cast<const bf16x8*>(Vl + v10o);
        const bf16x8 v11 = *reinterpret_cast<const bf16x8*>(Vl + v11o);

        __builtin_amdgcn_s_setprio(1);
        o0 = __builtin_amdgcn_mfma_f32_32x32x16_bf16(v00, pf0.v, o0, 0, 0, 0);
        o0 = __builtin_amdgcn_mfma_f32_32x32x16_bf16(v01, pf1.v, o0, 0, 0, 0);
        o1 = __builtin_amdgcn_mfma_f32_32x32x16_bf16(v10, pf0.v, o1, 0, 0, 0);
        o1 = __builtin_amdgcn_mfma_f32_32x32x16_bf16(v11, pf1.v, o1, 0, 0, 0);
        __builtin_amdgcn_s_setprio(0);
    }

    __syncthreads();   // staging/P regions dead in all waves -> overlay combine
    float* cmb = shm;
    float* my = cmb + ((size_t)w * 64 + lane) * 33;
#pragma unroll
    for (int i = 0; i < 16; ++i) { my[i] = o0[i]; my[16 + i] = o1[i]; }
    my[32] = lsum;
    __syncthreads();
    float tot[8] = {};
    float lt = 0.f;
#pragma unroll
    for (int w2 = 0; w2 < 4; ++w2) {
        const float* src = cmb + ((size_t)w2 * 64 + lane) * 33;
#pragma unroll
        for (int j = 0; j < 8; ++j) tot[j] += src[8 * w + j];
        lt += src[32];
    }
    lt += __shfl_xor(lt, 32);
    const float inv = 1.0f / lt;
    const int dbase = 32 * (w >> 1) + 16 * (w & 1) + 4 * hi;
    __bf16* cp = ctx + (size_t)(q0 + lq) * DM + h * HD;
    bf16x4 s0, s1;
#pragma unroll
    for (int j = 0; j < 4; ++j) {
        s0[j] = (__bf16)(tot[j] * inv);
        s1[j] = (__bf16)(tot[4 + j] * inv);
    }
    *reinterpret_cast<bf16x4*>(cp + dbase) = s0;
    *reinterpret_cast<bf16x4*>(cp + dbase + 8) = s1;
}

// ---------------------------------------------------------------------------
// Output projections, 224 blocks x 512 threads (split-K within block),
// chunked XCD swizzle (224 = 8x28). f32 out.
// ---------------------------------------------------------------------------
__global__ __launch_bounds__(512)
void gemm_out_all(const __bf16* __restrict__ c0, const __bf16* __restrict__ c1,
                  const __bf16* __restrict__ c2, const __bf16* __restrict__ Wob,
                  const float* __restrict__ bo, float* __restrict__ out) {
    __shared__ __align__(16) __bf16 lsh[32768];   // 64 KB
    const int bid = blockIdx.x;
    const int swz = (bid & 7) * 28 + (bid >> 3);     // 224 = 8*28
    int z, local, mblk;
    if      (swz < 128) { z = 0; local = swz;       mblk = 16; }
    else if (swz < 192) { z = 1; local = swz - 128; mblk = 8;  }
    else                { z = 2; local = swz - 192; mblk = 4;  }
    const __bf16* A; float* o;
    switch (z) {
        case 0:  A = c0; o = out;             break;
        case 1:  A = c1; o = out + 2048 * DM; break;
        default: A = c2; o = out + 3072 * DM; break;
    }
    const int rb = (local % mblk) * 128;
    const int cb = (local / mblk) * 128;
    const int tix = threadIdx.x;
    const int grp = tix >> 8;
    const int ltix = tix & 255;
    __bf16* lA = lsh + grp * 8192;
    __bf16* lB = lsh + 16384 + grp * 8192;
    f32x4 acc[4][4] = {};
    gemm_lds_core_g(A + grp * 512, Wob + grp * 512, rb, cb, ltix, lA, lB, acc);

    float* cmbF = (float*)lsh;
    const int lane = ltix & 63;
    const int wq = ltix >> 6;
    if (grp == 1) spillAcc(cmbF, wq, lane, acc);
    __syncthreads();
    if (grp == 1) return;
    addAcc(cmbF, wq, lane, acc);

    const int g = lane >> 4, t = lane & 15;
    const int rbw = rb + (wq >> 1) * 64;
    const int cbw = cb + (wq & 1) * 64;
#pragma unroll
    for (int ni = 0; ni < 4; ++ni) {
        const int col = cbw + ni * 16 + t;
        const float bb = bo[col];
#pragma unroll
        for (int mi = 0; mi < 4; ++mi) {
            const int row0 = rbw + mi * 16 + g * 4;
#pragma unroll
            for (int r = 0; r < 4; ++r)
                o[(size_t)(row0 + r) * DM + col] = acc[mi][ni][r] + bb;
        }
    }
}

// ---------------------------------------------------------------------------
extern "C" void kernel_launch(void* const* d_in, const int* in_sizes, int n_in,
                              void* d_out, int out_size, void* d_ws, size_t ws_size,
                              hipStream_t stream) {
    const float* x0 = (const float*)d_in[0];
    const float* x1 = (const float*)d_in[1];
    const float* x2 = (const float*)d_in[2];
    const float* Wq = (const float*)d_in[3];
    const float* bq = (const float*)d_in[4];
    const float* Wk = (const float*)d_in[5];
    const float* bk = (const float*)d_in[6];
    const float* Wv = (const float*)d_in[7];
    const float* bv = (const float*)d_in[8];
    const float* Wo = (const float*)d_in[9];
    const float* bo = (const float*)d_in[10];
    float* out = (float*)d_out;

    // bf16 workspace, ~39 MB
    __bf16* xb0 = (__bf16*)d_ws;        // 2M
    __bf16* xb1 = xb0 + 2 * M1;         // 1M
    __bf16* xb2 = xb1 + M1;             // 0.5M
    __bf16* Wqb = xb2 + M1 / 2;         // 3M
    __bf16* Wkb = Wqb + 3 * M1;         // 3M
    __bf16* Wvb = Wkb + 3 * M1;         // 1M
    __bf16* Wob = Wvb + M1;             // 1M
    __bf16* vt0 = Wob + M1;             // 2M
    __bf16* vt1 = vt0 + 2 * M1;         // 1M
    __bf16* vt2 = vt1 + M1;             // 0.5M
    __bf16* qb0 = vt2 + M1 / 2;         // 2M
    __bf16* kb0 = qb0 + 2 * M1;         // 2M
    __bf16* qb1 = kb0 + 2 * M1;         // 1M
    __bf16* kb1 = qb1 + M1;             // 1M
    __bf16* qb2 = kb1 + M1;             // 0.5M
    __bf16* kb2 = qb2 + M1 / 2;         // 0.5M

    // 1. convert everything to bf16
    cvt_all<<<5888, 256, 0, stream>>>(x0, x1, x2, Wq, Wk, Wv, Wo,
                                      xb0, xb1, xb2, Wqb, Wkb, Wvb, Wob);
    // 2. all pre-attention GEMMs (split-K 8-wave blocks, coalesced dbuf core)
    gemm_pre<<<576, 512, 0, stream>>>(xb0, xb1, xb2, Wqb, Wkb, Wvb,
                                      bq, bk, bv,
                                      qb0, kb0, qb1, kb1, qb2, kb2,
                                      vt0, vt1, vt2);
    // 3. attention: split-wait K/V staging + setprio, split-K, XCD affinity
    attn_all<<<1792, 256, 0, stream>>>(qb0, kb0, vt0, qb0,
                                       qb1, kb1, vt1, qb1,
                                       qb2, kb2, vt2, qb2);
    // 4. output projections (split-K 8-wave blocks), f32 into d_out
    gemm_out_all<<<224, 512, 0, stream>>>(qb0, qb1, qb2, Wob, bo, out);
}

// Round 19
// 113.981 us; speedup vs baseline: 1.5492x; 1.0936x over previous
//
#include <hip/hip_runtime.h>
#include <hip/hip_bf16.h>
#include <math.h>

typedef __bf16 bf16x8 __attribute__((ext_vector_type(8)));
typedef __bf16 bf16x4 __attribute__((ext_vector_type(4)));
typedef __bf16 bf16x2 __attribute__((ext_vector_type(2)));
typedef float f32x4 __attribute__((ext_vector_type(4)));
typedef float f32x16 __attribute__((ext_vector_type(16)));

static constexpr int DM = 1024;    // d_model
static constexpr int HD = 64;      // head dim
static constexpr size_t M1 = 1024 * 1024;

// pack two f32 -> u32 of two bf16 (compiler emits v_cvt_pk_bf16_f32)
__device__ __forceinline__ unsigned pk2(float a, float b) {
    union { __bf16 h[2]; unsigned u; } t;
    t.h[0] = (__bf16)a; t.h[1] = (__bf16)b;
    return t.u;
}

// async global->LDS, 16 B per lane; LDS dest = wave-uniform base + lane*16
typedef const __attribute__((address_space(1))) unsigned int* gp_t;
typedef __attribute__((address_space(3))) unsigned int* lp_t;
__device__ __forceinline__ void gload_lds16(const void* g, void* l) {
    __builtin_amdgcn_global_load_lds((gp_t)g, (lp_t)l, 16, 0, 0);
}

// ---------------------------------------------------------------------------
// Fused f32->bf16 convert of all 7 tensors, one launch.
// ---------------------------------------------------------------------------
__global__ void cvt_all(const float* __restrict__ x0, const float* __restrict__ x1,
                        const float* __restrict__ x2, const float* __restrict__ Wq,
                        const float* __restrict__ Wk, const float* __restrict__ Wv,
                        const float* __restrict__ Wo,
                        __bf16* __restrict__ xb0, __bf16* __restrict__ xb1,
                        __bf16* __restrict__ xb2, __bf16* __restrict__ Wqb,
                        __bf16* __restrict__ Wkb, __bf16* __restrict__ Wvb,
                        __bf16* __restrict__ Wob) {
    size_t i = (size_t)(blockIdx.x * blockDim.x + threadIdx.x) * 8;
    const float* in; __bf16* outp; size_t off;
    if      (i < 2 * M1)            { in = x0; outp = xb0; off = i; }
    else if (i < 3 * M1)            { in = x1; outp = xb1; off = i - 2 * M1; }
    else if (i < 3 * M1 + M1 / 2)   { in = x2; outp = xb2; off = i - 3 * M1; }
    else if (i < 6 * M1 + M1 / 2)   { in = Wq; outp = Wqb; off = i - (3 * M1 + M1 / 2); }
    else if (i < 9 * M1 + M1 / 2)   { in = Wk; outp = Wkb; off = i - (6 * M1 + M1 / 2); }
    else if (i < 10 * M1 + M1 / 2)  { in = Wv; outp = Wvb; off = i - (9 * M1 + M1 / 2); }
    else if (i < 11 * M1 + M1 / 2)  { in = Wo; outp = Wob; off = i - (10 * M1 + M1 / 2); }
    else return;
    const float4 a = *reinterpret_cast<const float4*>(in + off);
    const float4 b = *reinterpret_cast<const float4*>(in + off + 4);
    bf16x8 r;
    r[0] = (__bf16)a.x; r[1] = (__bf16)a.y; r[2] = (__bf16)a.z; r[3] = (__bf16)a.w;
    r[4] = (__bf16)b.x; r[5] = (__bf16)b.y; r[6] = (__bf16)b.z; r[7] = (__bf16)b.w;
    *reinterpret_cast<bf16x8*>(outp + off) = r;
}

// ---------------------------------------------------------------------------
// GEMM half-K core (r13-proven layout, K-range 512): 128x128 tile, one
// 4-wave GROUP (ltix 0..255) of 64x64 waves, BK=32, dbuf LDS, coalesced
// staging + both-sides XOR swizzle. (verified r17: gemm_pre 52.6 us)
// C/D layout: row=(lane>>4)*4+reg, col=lane&15 (m89-verified)
// ---------------------------------------------------------------------------
__device__ __forceinline__ void gemm_lds_core_g(const __bf16* __restrict__ A,
                                                const __bf16* __restrict__ W,
                                                int rb, int cb, int ltix,
                                                __bf16* lA, __bf16* lB,
                                                f32x4 (&acc)[4][4]) {
    const int lane = ltix & 63;
    const int w = ltix >> 6;
    const int g = lane >> 4, t = lane & 15;
    const int r0 = ltix >> 2;
    const int r1 = r0 + 64;
    const int c0 = (ltix & 3) ^ ((r0 ^ (r0 >> 2)) & 3);
    const int c1 = (ltix & 3) ^ ((r1 ^ (r1 >> 2)) & 3);
    const __bf16* a0 = A + (size_t)(rb + r0) * DM + c0 * 8;
    const __bf16* a1 = A + (size_t)(rb + r1) * DM + c1 * 8;
    const __bf16* b0 = W + (size_t)(cb + r0) * DM + c0 * 8;
    const __bf16* b1 = W + (size_t)(cb + r1) * DM + c1 * 8;
    const int d0 = w * 512;
    const int d1 = 2048 + w * 512;
    const int rw = (w >> 1) * 64, cw = (w & 1) * 64;
    int roA[4], roB[4];
#pragma unroll
    for (int i = 0; i < 4; ++i) {
        const int ra = rw + i * 16 + t;
        const int rbr = cw + i * 16 + t;
        roA[i] = ra * 32 + ((g ^ ((ra ^ (ra >> 2)) & 3)) * 8);
        roB[i] = rbr * 32 + ((g ^ ((rbr ^ (rbr >> 2)) & 3)) * 8);
    }

    gload_lds16(a0, lA + d0);
    gload_lds16(a1, lA + d1);
    gload_lds16(b0, lB + d0);
    gload_lds16(b1, lB + d1);
    __syncthreads();

    int cur = 0;
    for (int kk = 0; kk < 512; kk += 32) {
        if (kk + 32 < 512) {
            __bf16* nA = lA + (cur ^ 1) * 4096;
            __bf16* nB = lB + (cur ^ 1) * 4096;
            gload_lds16(a0 + kk + 32, nA + d0);
            gload_lds16(a1 + kk + 32, nA + d1);
            gload_lds16(b0 + kk + 32, nB + d0);
            gload_lds16(b1 + kk + 32, nB + d1);
        }
        const __bf16* bA = lA + cur * 4096;
        const __bf16* bB = lB + cur * 4096;
        bf16x8 af[4], bfr[4];
#pragma unroll
        for (int i = 0; i < 4; ++i) {
            af[i]  = *reinterpret_cast<const bf16x8*>(bA + roA[i]);
            bfr[i] = *reinterpret_cast<const bf16x8*>(bB + roB[i]);
        }
#pragma unroll
        for (int mi = 0; mi < 4; ++mi)
#pragma unroll
            for (int ni = 0; ni < 4; ++ni)
                acc[mi][ni] = __builtin_amdgcn_mfma_f32_16x16x32_bf16(af[mi], bfr[ni], acc[mi][ni], 0, 0, 0);
        __syncthreads();
        cur ^= 1;
    }
}

// split-K combine helpers: cmbF[i][wq*64+lane] — conflict-free rows of 256 f32
__device__ __forceinline__ void spillAcc(float* cmbF, int wq, int lane,
                                         const f32x4 (&acc)[4][4]) {
#pragma unroll
    for (int i = 0; i < 16; ++i) {
        const f32x4 v = acc[i >> 2][i & 3];
#pragma unroll
        for (int r = 0; r < 4; ++r)
            cmbF[(size_t)(i * 4 + r) * 256 + wq * 64 + lane] = v[r];
    }
}
__device__ __forceinline__ void addAcc(const float* cmbF, int wq, int lane,
                                       f32x4 (&acc)[4][4]) {
#pragma unroll
    for (int i = 0; i < 16; ++i) {
#pragma unroll
        for (int r = 0; r < 4; ++r)
            acc[i >> 2][i & 3][r] += cmbF[(size_t)(i * 4 + r) * 256 + wq * 64 + lane];
    }
}

// ---------------------------------------------------------------------------
// All pre-attention GEMMs (verbatim r17): 576 blocks x 512 threads, split-K
// within block, chunked XCD swizzle.
// ---------------------------------------------------------------------------
__global__ __launch_bounds__(512)
void gemm_pre(const __bf16* __restrict__ xb0, const __bf16* __restrict__ xb1,
              const __bf16* __restrict__ xb2, const __bf16* __restrict__ Wqb,
              const __bf16* __restrict__ Wkb, const __bf16* __restrict__ Wvb,
              const float* __restrict__ bq, const float* __restrict__ bk,
              const float* __restrict__ bv,
              __bf16* __restrict__ qb0, __bf16* __restrict__ kb0,
              __bf16* __restrict__ qb1, __bf16* __restrict__ kb1,
              __bf16* __restrict__ qb2, __bf16* __restrict__ kb2,
              __bf16* __restrict__ vt0, __bf16* __restrict__ vt1,
              __bf16* __restrict__ vt2) {
    __shared__ __align__(16) __bf16 lsh[32768];   // 64 KB
    const int bid = blockIdx.x;
    const int swz = (bid & 7) * 72 + (bid >> 3);
    int z, local, mblk;
    if      (swz < 128) { z = 0; local = swz;       mblk = 16; }
    else if (swz < 256) { z = 1; local = swz - 128; mblk = 16; }
    else if (swz < 320) { z = 2; local = swz - 256; mblk = 8;  }
    else if (swz < 384) { z = 3; local = swz - 320; mblk = 8;  }
    else if (swz < 416) { z = 4; local = swz - 384; mblk = 4;  }
    else if (swz < 448) { z = 5; local = swz - 416; mblk = 4;  }
    else                { z = 6; local = swz - 448; mblk = 16; }
    const __bf16* A; const __bf16* W; const float* bias; __bf16* out;
    switch (z) {
        case 0:  A = xb0; W = Wqb;          bias = bq;        out = qb0; break;
        case 1:  A = xb0; W = Wkb;          bias = bk;        out = kb0; break;
        case 2:  A = xb1; W = Wqb + M1;     bias = bq + 1024; out = qb1; break;
        case 3:  A = xb1; W = Wkb + M1;     bias = bk + 1024; out = kb1; break;
        case 4:  A = xb2; W = Wqb + 2 * M1; bias = bq + 2048; out = qb2; break;
        case 5:  A = xb2; W = Wkb + 2 * M1; bias = bk + 2048; out = kb2; break;
        default: A = xb0; W = Wvb;          bias = bv;        out = nullptr; break;
    }
    const int rb = (local % mblk) * 128;
    const int cb = (local / mblk) * 128;
    const int tix = threadIdx.x;
    const int grp = tix >> 8;
    const int ltix = tix & 255;
    __bf16* lA = lsh + grp * 8192;
    __bf16* lB = lsh + 16384 + grp * 8192;
    f32x4 acc[4][4] = {};
    gemm_lds_core_g(A + grp * 512, W + grp * 512, rb, cb, ltix, lA, lB, acc);

    float* cmbF = (float*)lsh;
    const int lane = ltix & 63;
    const int wq = ltix >> 6;
    if (grp == 1) spillAcc(cmbF, wq, lane, acc);
    __syncthreads();
    if (grp == 1) return;
    addAcc(cmbF, wq, lane, acc);

    const int g = lane >> 4, t = lane & 15;
    const int rbw = rb + (wq >> 1) * 64;
    const int cbw = cb + (wq & 1) * 64;

    if (z == 6) {
#pragma unroll
        for (int ni = 0; ni < 4; ++ni) {
            const int col = cbw + ni * 16 + t;
            const float bb = bias[col];
#pragma unroll
            for (int mi = 0; mi < 4; ++mi) {
                const int row0 = rbw + mi * 16 + g * 4;
                const f32x4 a = acc[mi][ni];
                bf16x4 pk;
#pragma unroll
                for (int r = 0; r < 4; ++r) pk[r] = (__bf16)(a[r] + bb);
                *reinterpret_cast<bf16x4*>(vt0 + (size_t)col * 2048 + row0) = pk;
                bf16x2 p2;
                p2[0] = (__bf16)(0.5f * (a[0] + a[1]) + bb);
                p2[1] = (__bf16)(0.5f * (a[2] + a[3]) + bb);
                *reinterpret_cast<bf16x2*>(vt1 + (size_t)col * 1024 + row0 / 2) = p2;
                vt2[(size_t)col * 512 + row0 / 4] =
                    (__bf16)(0.25f * (a[0] + a[1] + a[2] + a[3]) + bb);
            }
        }
    } else {
        const float qmul = (z & 1) ? 1.0f : 0.125f;
        const float ps = (float)(1 << (z >> 1));
#pragma unroll
        for (int ni = 0; ni < 2; ++ni) {
            const int j = ni * 16 + t;
            const float invf = __expf(-(float)j * 0.28782313662425576f);
            const float b1 = bias[cbw + j];
            const float b2 = bias[cbw + j + 32];
#pragma unroll
            for (int mi = 0; mi < 4; ++mi) {
#pragma unroll
                for (int r = 0; r < 4; ++r) {
                    const int row = rbw + mi * 16 + g * 4 + r;
                    float c, s;
                    __sincosf((float)row * ps * invf, &s, &c);
                    const float x1 = acc[mi][ni][r] + b1;
                    const float x2 = acc[mi][ni + 2][r] + b2;
                    out[(size_t)row * DM + cbw + j]      = (__bf16)((x1 * c - x2 * s) * qmul);
                    out[(size_t)row * DM + cbw + j + 32] = (__bf16)((x1 * s + x2 * c) * qmul);
                }
            }
        }
    }
}

// ---------------------------------------------------------------------------
// MFMA flash attention v8.1: balanced job-pair blocks (single round) with the
// r17-VERIFIED iteration body (no cross-iteration in-flight LDS writes).
// Grid = 896 = 8 XCD x 112; per XCD: 2 heads x (32 s0 + 16 s1 + 8 s2 pairs).
// Each block runs TWO jobs (same scale/head, qt = x and nq-1-x) -> combined
// ktiles = nq+1 = constant per scale (perfect balance).
// Per iteration: issue K -> issue V -> vmcnt(4) (K ready; V in flight) ->
// QK^T -> softmax -> P-bounce -> vmcnt(0) -> PV. setprio around MFMA.
// ---------------------------------------------------------------------------
__global__ __launch_bounds__(256)
void attn_all(const __bf16* __restrict__ qb0, const __bf16* __restrict__ kb0,
              const __bf16* __restrict__ vt0, __bf16* __restrict__ ctx0,
              const __bf16* __restrict__ qb1, const __bf16* __restrict__ kb1,
              const __bf16* __restrict__ vt1, __bf16* __restrict__ ctx1,
              const __bf16* __restrict__ qb2, const __bf16* __restrict__ kb2,
              const __bf16* __restrict__ vt2, __bf16* __restrict__ ctx2) {
    __shared__ __align__(16) float shm[4 * 64 * 33];    // 33.8 KB
    const int bid = blockIdx.x;
    const int p = bid >> 3;                 // 0..111 within XCD
    const int h = (bid & 7) * 2 + (p / 56); // head; 2 heads per XCD
    const int rem = p % 56;
    const __bf16 *qb, *kb, *vt; __bf16* ctx; int N, nq, x;
    if (rem < 32)      { qb = qb0; kb = kb0; vt = vt0; ctx = ctx0; N = 2048; nq = 64; x = rem; }
    else if (rem < 48) { qb = qb1; kb = kb1; vt = vt1; ctx = ctx1; N = 1024; nq = 32; x = rem - 32; }
    else               { qb = qb2; kb = kb2; vt = vt2; ctx = ctx2; N = 512;  nq = 16; x = rem - 48; }
    const int lane = threadIdx.x & 63;
    const int w = threadIdx.x >> 6;
    const int lq = lane & 31;
    const int hi = lane >> 5;

    __bf16* Kl = (__bf16*)shm + (size_t)w * 4096;   // [32][64 elems] (4 KB)
    __bf16* Vl = Kl + 2048;                          // [64][32 elems] (4 KB)

    const int krow = lane >> 3, kch = lane & 7;      // K: 8 lanes/row (128B)
    const int vrow = lane >> 2, vch = lane & 3;      // V: 4 lanes/row (64B)

    int koff[4];
#pragma unroll
    for (int dc = 0; dc < 4; ++dc)
        koff[dc] = lq * 64 + (((dc * 2 + hi) ^ (lq & 7)) * 8);
    const int v00o = lq * 32 + ((hi ^ (lq & 3)) * 8);
    const int v01o = lq * 32 + (((2 + hi) ^ (lq & 3)) * 8);
    const int v10o = (32 + lq) * 32 + ((hi ^ (lq & 3)) * 8);
    const int v11o = (32 + lq) * 32 + (((2 + hi) ^ (lq & 3)) * 8);

    unsigned* pw = (unsigned*)Kl + lq * 18;          // P-bounce inside K region
    const __bf16* prb = (const __bf16*)pw;

    for (int jj = 0; jj < 2; ++jj) {
        const int qt = jj ? (nq - 1 - x) : x;
        const int q0 = qt * 32;
        const int ktiles = qt + 1;

        // Q B-frags for this job
        const __bf16* qp = qb + (size_t)(q0 + lq) * DM + h * HD + hi * 8;
        bf16x8 qf[4];
#pragma unroll
        for (int dc = 0; dc < 4; ++dc)
            qf[dc] = *reinterpret_cast<const bf16x8*>(qp + dc * 16);

        f32x16 o0 = {}, o1 = {};
        float lsum = 0.f;

        for (int kt = w; kt < ktiles; kt += 4) {
            const int j0 = kt * 32;
            // issue K loads first (oldest), then V
#pragma unroll
            for (int j = 0; j < 4; ++j) {
                const int row = j * 8 + krow;
                gload_lds16(kb + (size_t)(j0 + row) * DM + h * HD + ((kch ^ (row & 7)) * 8),
                            Kl + j * 512);
            }
#pragma unroll
            for (int j = 0; j < 4; ++j) {
                const int row = j * 16 + vrow;
                gload_lds16(vt + (size_t)(h * HD + row) * N + j0 + ((vch ^ (row & 3)) * 8),
                            Vl + j * 512);
            }
            // K ready (oldest 4); V stays in flight through QK+softmax
            asm volatile("s_waitcnt vmcnt(4)" ::: "memory");
            bf16x8 kf[4];
#pragma unroll
            for (int dc = 0; dc < 4; ++dc)
                kf[dc] = *reinterpret_cast<const bf16x8*>(Kl + koff[dc]);

            f32x16 pfr = {};
            __builtin_amdgcn_s_setprio(1);
            pfr = __builtin_amdgcn_mfma_f32_32x32x16_bf16(kf[0], qf[0], pfr, 0, 0, 0);
            pfr = __builtin_amdgcn_mfma_f32_32x32x16_bf16(kf[1], qf[1], pfr, 0, 0, 0);
            pfr = __builtin_amdgcn_mfma_f32_32x32x16_bf16(kf[2], qf[2], pfr, 0, 0, 0);
            pfr = __builtin_amdgcn_mfma_f32_32x32x16_bf16(kf[3], qf[3], pfr, 0, 0, 0);
            __builtin_amdgcn_s_setprio(0);

#pragma unroll
            for (int r = 0; r < 16; ++r) {
                const int key = j0 + (r & 3) + 8 * (r >> 2) + 4 * hi;
                pfr[r] = (key <= q0 + lq) ? __expf(pfr[r]) : 0.f;
                lsum += pfr[r];
            }

            // P-bounce (K region dead: kf in registers)
            pw[2 * hi]      = pk2(pfr[0],  pfr[1]);
            pw[2 * hi + 1]  = pk2(pfr[2],  pfr[3]);
            pw[4 + 2 * hi]  = pk2(pfr[4],  pfr[5]);
            pw[5 + 2 * hi]  = pk2(pfr[6],  pfr[7]);
            pw[8 + 2 * hi]  = pk2(pfr[8],  pfr[9]);
            pw[9 + 2 * hi]  = pk2(pfr[10], pfr[11]);
            pw[12 + 2 * hi] = pk2(pfr[12], pfr[13]);
            pw[13 + 2 * hi] = pk2(pfr[14], pfr[15]);
            union U8 { bf16x4 half[2]; bf16x8 v; };
            U8 pf0, pf1;
            pf0.half[0] = *reinterpret_cast<const bf16x4*>(prb + hi * 8);
            pf0.half[1] = *reinterpret_cast<const bf16x4*>(prb + hi * 8 + 4);
            pf1.half[0] = *reinterpret_cast<const bf16x4*>(prb + 16 + hi * 8);
            pf1.half[1] = *reinterpret_cast<const bf16x4*>(prb + 16 + hi * 8 + 4);

            // V ready
            asm volatile("s_waitcnt vmcnt(0)" ::: "memory");
            const bf16x8 v00 = *reinterpret_cast<const bf16x8*>(Vl + v00o);
            const bf16x8 v01 = *reinterpret_cast<const bf16x8*>(Vl + v01o);
            const bf16x8 v10 = *reinterpret_cast<const bf16x8*>(Vl + v10o);
            const bf16x8 v11 = *reinterpret_cast<const bf16x8*>(Vl + v11o);

            __builtin_amdgcn_s_setprio(1);
            o0 = __builtin_amdgcn_mfma_f32_32x32x16_bf16(v00, pf0.v, o0, 0, 0, 0);
            o0 = __builtin_amdgcn_mfma_f32_32x32x16_bf16(v01, pf1.v, o0, 0, 0, 0);
            o1 = __builtin_amdgcn_mfma_f32_32x32x16_bf16(v10, pf0.v, o1, 0, 0, 0);
            o1 = __builtin_amdgcn_mfma_f32_32x32x16_bf16(v11, pf1.v, o1, 0, 0, 0);
            __builtin_amdgcn_s_setprio(0);
        }

        __syncthreads();   // staging/P dead in all waves -> overlay combine
        float* cmb = shm;
        float* my = cmb + ((size_t)w * 64 + lane) * 33;
#pragma unroll
        for (int i = 0; i < 16; ++i) { my[i] = o0[i]; my[16 + i] = o1[i]; }
        my[32] = lsum;
        __syncthreads();
        float tot[8] = {};
        float lt = 0.f;
#pragma unroll
        for (int w2 = 0; w2 < 4; ++w2) {
            const float* src = cmb + ((size_t)w2 * 64 + lane) * 33;
#pragma unroll
            for (int j = 0; j < 8; ++j) tot[j] += src[8 * w + j];
            lt += src[32];
        }
        lt += __shfl_xor(lt, 32);
        const float inv = 1.0f / lt;
        const int dbase = 32 * (w >> 1) + 16 * (w & 1) + 4 * hi;
        __bf16* cp = ctx + (size_t)(q0 + lq) * DM + h * HD;
        bf16x4 s0, s1;
#pragma unroll
        for (int j = 0; j < 4; ++j) {
            s0[j] = (__bf16)(tot[j] * inv);
            s1[j] = (__bf16)(tot[4 + j] * inv);
        }
        *reinterpret_cast<bf16x4*>(cp + dbase) = s0;
        *reinterpret_cast<bf16x4*>(cp + dbase + 8) = s1;
        __syncthreads();   // combine reads done before next job's staging
    }
}

// ---------------------------------------------------------------------------
// Output projections (verbatim r17): 224 blocks x 512 threads, split-K
// within block, chunked XCD swizzle. f32 out.
// ---------------------------------------------------------------------------
__global__ __launch_bounds__(512)
void gemm_out_all(const __bf16* __restrict__ c0, const __bf16* __restrict__ c1,
                  const __bf16* __restrict__ c2, const __bf16* __restrict__ Wob,
                  const float* __restrict__ bo, float* __restrict__ out) {
    __shared__ __align__(16) __bf16 lsh[32768];   // 64 KB
    const int bid = blockIdx.x;
    const int swz = (bid & 7) * 28 + (bid >> 3);     // 224 = 8*28
    int z, local, mblk;
    if      (swz < 128) { z = 0; local = swz;       mblk = 16; }
    else if (swz < 192) { z = 1; local = swz - 128; mblk = 8;  }
    else                { z = 2; local = swz - 192; mblk = 4;  }
    const __bf16* A; float* o;
    switch (z) {
        case 0:  A = c0; o = out;             break;
        case 1:  A = c1; o = out + 2048 * DM; break;
        default: A = c2; o = out + 3072 * DM; break;
    }
    const int rb = (local % mblk) * 128;
    const int cb = (local / mblk) * 128;
    const int tix = threadIdx.x;
    const int grp = tix >> 8;
    const int ltix = tix & 255;
    __bf16* lA = lsh + grp * 8192;
    __bf16* lB = lsh + 16384 + grp * 8192;
    f32x4 acc[4][4] = {};
    gemm_lds_core_g(A + grp * 512, Wob + grp * 512, rb, cb, ltix, lA, lB, acc);

    float* cmbF = (float*)lsh;
    const int lane = ltix & 63;
    const int wq = ltix >> 6;
    if (grp == 1) spillAcc(cmbF, wq, lane, acc);
    __syncthreads();
    if (grp == 1) return;
    addAcc(cmbF, wq, lane, acc);

    const int g = lane >> 4, t = lane & 15;
    const int rbw = rb + (wq >> 1) * 64;
    const int cbw = cb + (wq & 1) * 64;
#pragma unroll
    for (int ni = 0; ni < 4; ++ni) {
        const int col = cbw + ni * 16 + t;
        const float bb = bo[col];
#pragma unroll
        for (int mi = 0; mi < 4; ++mi) {
            const int row0 = rbw + mi * 16 + g * 4;
#pragma unroll
            for (int r = 0; r < 4; ++r)
                o[(size_t)(row0 + r) * DM + col] = acc[mi][ni][r] + bb;
        }
    }
}

// ---------------------------------------------------------------------------
extern "C" void kernel_launch(void* const* d_in, const int* in_sizes, int n_in,
                              void* d_out, int out_size, void* d_ws, size_t ws_size,
                              hipStream_t stream) {
    const float* x0 = (const float*)d_in[0];
    const float* x1 = (const float*)d_in[1];
    const float* x2 = (const float*)d_in[2];
    const float* Wq = (const float*)d_in[3];
    const float* bq = (const float*)d_in[4];
    const float* Wk = (const float*)d_in[5];
    const float* bk = (const float*)d_in[6];
    const float* Wv = (const float*)d_in[7];
    const float* bv = (const float*)d_in[8];
    const float* Wo = (const float*)d_in[9];
    const float* bo = (const float*)d_in[10];
    float* out = (float*)d_out;

    // bf16 workspace, ~39 MB
    __bf16* xb0 = (__bf16*)d_ws;        // 2M
    __bf16* xb1 = xb0 + 2 * M1;         // 1M
    __bf16* xb2 = xb1 + M1;             // 0.5M
    __bf16* Wqb = xb2 + M1 / 2;         // 3M
    __bf16* Wkb = Wqb + 3 * M1;         // 3M
    __bf16* Wvb = Wkb + 3 * M1;         // 1M
    __bf16* Wob = Wvb + M1;             // 1M
    __bf16* vt0 = Wob + M1;             // 2M
    __bf16* vt1 = vt0 + 2 * M1;         // 1M
    __bf16* vt2 = vt1 + M1;             // 0.5M
    __bf16* qb0 = vt2 + M1 / 2;         // 2M
    __bf16* kb0 = qb0 + 2 * M1;         // 2M
    __bf16* qb1 = kb0 + 2 * M1;         // 1M
    __bf16* kb1 = qb1 + M1;             // 1M
    __bf16* qb2 = kb1 + M1;             // 0.5M
    __bf16* kb2 = qb2 + M1 / 2;         // 0.5M

    // 1. convert everything to bf16
    cvt_all<<<5888, 256, 0, stream>>>(x0, x1, x2, Wq, Wk, Wv, Wo,
                                      xb0, xb1, xb2, Wqb, Wkb, Wvb, Wob);
    // 2. all pre-attention GEMMs (split-K 8-wave blocks)
    gemm_pre<<<576, 512, 0, stream>>>(xb0, xb1, xb2, Wqb, Wkb, Wvb,
                                      bq, bk, bv,
                                      qb0, kb0, qb1, kb1, qb2, kb2,
                                      vt0, vt1, vt2);
    // 3. attention: balanced job-pair blocks (r17 body), XCD affinity
    attn_all<<<896, 256, 0, stream>>>(qb0, kb0, vt0, qb0,
                                      qb1, kb1, vt1, qb1,
                                      qb2, kb2, vt2, qb2);
    // 4. output projections (split-K 8-wave blocks), f32 into d_out
    gemm_out_all<<<224, 512, 0, stream>>>(qb0, qb1, qb2, Wob, bo, out);
}